// Round 11
// baseline (341.279 us; speedup 1.0000x reference)
//
#include <hip/hip_runtime.h>

// Problem constants (fixed by the reference).
static constexpr int kB  = 2;
static constexpr int kL  = 4096;   // source sequence length
static constexpr int kD  = 1024;
static constexpr int kH  = 16;
static constexpr int kDH = 64;
static constexpr int kM  = 256;
static constexpr int kN  = kB * kL;              // 8192 deduplicated rows
static constexpr float kScale    = 0.35355339059327373f;  // DH^-0.25
static constexpr float kInvSqrtM = 0.0625f;               // M^-0.5
static constexpr float kEps   = 1e-6f;
static constexpr float kLnEps = 1e-5f;

typedef __attribute__((ext_vector_type(8))) short short8;   // 8 bf16 (4 VGPRs)
typedef __attribute__((ext_vector_type(4))) float f32x4;

__device__ __forceinline__ float bf2f(unsigned short h) {
  union { unsigned int u; float f; } c;
  c.u = ((unsigned int)h) << 16;
  return c.f;
}
__device__ __forceinline__ unsigned short f2bf(float f) {
  union { float f; unsigned int u; } c;
  c.f = f;
  unsigned int u = c.u;
  u += 0x7fffu + ((u >> 16) & 1u);   // round-to-nearest-even
  return (unsigned short)(u >> 16);
}

// async global->LDS, 16 B per lane; LDS dest = wave-uniform base + lane*16.
__device__ __forceinline__ void gload_lds16(const unsigned short* g,
                                            unsigned short* l) {
  __builtin_amdgcn_global_load_lds(
      (const __attribute__((address_space(1))) unsigned int*)g,
      (__attribute__((address_space(3))) unsigned int*)l, 16, 0, 0);
}

// Bijective XCD-chunked block remap (nwg must be a multiple of 8).
__device__ __forceinline__ void xcd_swizzle(int& bx, int& by) {
  const int nwg = gridDim.x * gridDim.y;
  const int bid = blockIdx.x + gridDim.x * blockIdx.y;
  const int cpx = nwg >> 3;
  const int sb  = (bid & 7) * cpx + (bid >> 3);
  bx = sb % gridDim.x;
  by = sb / gridDim.x;
}

// ---------------------------------------------------------------------------
// casts
// ---------------------------------------------------------------------------
__global__ __launch_bounds__(256) void cast_bf16_kernel(
    const float* __restrict__ in, unsigned short* __restrict__ out)
{
  const int i = blockIdx.x * 256 + threadIdx.x;
  float4 v = ((const float4*)in)[i];
  ushort4 o;
  o.x = f2bf(v.x); o.y = f2bf(v.y); o.z = f2bf(v.z); o.w = f2bf(v.w);
  ((ushort4*)out)[i] = o;
}

// All four weight transposes in one launch. z in {0,1,2}: Wq/Wk/Wv into
// WqkvT[3072][1024] at row offset z*1024; z==3: Wo into WoT.
__global__ __launch_bounds__(256) void transpose_cast4_kernel(
    const float* __restrict__ W0, const float* __restrict__ W1,
    const float* __restrict__ W2, const float* __restrict__ W3,
    unsigned short* __restrict__ WqkvT, unsigned short* __restrict__ WoT)
{
  __shared__ float tile[32][33];
  const int z = blockIdx.z;
  const float* W = (z == 0) ? W0 : (z == 1) ? W1 : (z == 2) ? W2 : W3;
  unsigned short* WT = (z < 3) ? (WqkvT + (size_t)z * kD * kD) : WoT;
  const int n0 = blockIdx.x * 32, k0 = blockIdx.y * 32;
  const int t = threadIdx.x, kk = t >> 5, nn = t & 31;
#pragma unroll
  for (int i = 0; i < 4; ++i)
    tile[kk + i * 8][nn] = W[(size_t)(k0 + kk + i * 8) * kD + n0 + nn];
  __syncthreads();
#pragma unroll
  for (int i = 0; i < 4; ++i)
    WT[(size_t)(n0 + kk + i * 8) * kD + k0 + nn] = f2bf(tile[nn][kk + i * 8]);
}

// ---------------------------------------------------------------------------
// Merged Q+K projection GEMM (m97 single-buffer structure, XCD-swizzled).
// ---------------------------------------------------------------------------
__global__ __launch_bounds__(256) void gemm_qk_mfma(
    const unsigned short* __restrict__ A, const unsigned short* __restrict__ BT,
    unsigned short* __restrict__ Qb, unsigned short* __restrict__ Kb)
{
  __shared__ unsigned short As[128 * 32];
  __shared__ unsigned short Bs[128 * 32];
  const int tid = threadIdx.x, lane = tid & 63, w = tid >> 6;
  const int q = lane >> 4, c = lane & 15;
  const int wr = (w >> 1) * 64, wc = (w & 1) * 64;
  int bx, by; xcd_swizzle(bx, by);
  const int row0 = by * 128, col0 = bx * 128;
  const int lrow = lane >> 2, lcol = (lane & 3) * 8;

  f32x4 acc[4][4];
#pragma unroll
  for (int i = 0; i < 4; ++i)
#pragma unroll
    for (int j = 0; j < 4; ++j) acc[i][j] = (f32x4)0.f;

  for (int k0 = 0; k0 < kD; k0 += 32) {
#pragma unroll
    for (int i = 0; i < 2; ++i) {
      const int r0 = w * 32 + i * 16;
      gload_lds16(&A[(size_t)(row0 + r0 + lrow) * kD + k0 + lcol], &As[r0 * 32]);
      gload_lds16(&BT[(size_t)(col0 + r0 + lrow) * kD + k0 + lcol], &Bs[r0 * 32]);
    }
    __syncthreads();
    short8 av[4], bv[4];
#pragma unroll
    for (int i = 0; i < 4; ++i)
      av[i] = *(const short8*)&As[(wr + i * 16 + c) * 32 + q * 8];
#pragma unroll
    for (int j = 0; j < 4; ++j)
      bv[j] = *(const short8*)&Bs[(wc + j * 16 + c) * 32 + q * 8];
#pragma unroll
    for (int i = 0; i < 4; ++i)
#pragma unroll
      for (int j = 0; j < 4; ++j)
        acc[i][j] = __builtin_amdgcn_mfma_f32_16x16x32_bf16(
            av[i], bv[j], acc[i][j], 0, 0, 0);
    __syncthreads();
  }

  unsigned short* O = (col0 < 1024) ? Qb : Kb;
  const int cl0 = col0 & 1023;
#pragma unroll
  for (int i = 0; i < 4; ++i)
#pragma unroll
    for (int j = 0; j < 4; ++j)
#pragma unroll
      for (int r = 0; r < 4; ++r) {
        const int row = row0 + wr + i * 16 + q * 4 + r;
        const int col = cl0 + wc + j * 16 + c;
        O[(size_t)row * kD + col] = f2bf(kScale * acc[i][j][r]);
      }
}

// ---------------------------------------------------------------------------
// V^T projection GEMM via swapped operands (r8-proven single-buffer).
// ---------------------------------------------------------------------------
__global__ __launch_bounds__(256) void gemm_vt_mfma(
    const unsigned short* __restrict__ A, const unsigned short* __restrict__ BT,
    unsigned short* __restrict__ VT)
{
  __shared__ unsigned short As[128 * 32];
  __shared__ unsigned short Bs[128 * 32];
  const int tid = threadIdx.x, lane = tid & 63, w = tid >> 6;
  const int q = lane >> 4, c = lane & 15;
  const int wr = (w >> 1) * 64, wc = (w & 1) * 64;
  int bx, by; xcd_swizzle(bx, by);
  const int row0 = bx * 128, col0 = by * 128;   // rows = WvT (8), cols = l (64)
  const int lrow = lane >> 2, lcol = (lane & 3) * 8;

  f32x4 acc[4][4];
#pragma unroll
  for (int i = 0; i < 4; ++i)
#pragma unroll
    for (int j = 0; j < 4; ++j) acc[i][j] = (f32x4)0.f;

  for (int k0 = 0; k0 < kD; k0 += 32) {
#pragma unroll
    for (int i = 0; i < 2; ++i) {
      const int r0 = w * 32 + i * 16;
      gload_lds16(&A[(size_t)(row0 + r0 + lrow) * kD + k0 + lcol], &As[r0 * 32]);
      gload_lds16(&BT[(size_t)(col0 + r0 + lrow) * kD + k0 + lcol], &Bs[r0 * 32]);
    }
    __syncthreads();
    short8 av[4], bv[4];
#pragma unroll
    for (int i = 0; i < 4; ++i)
      av[i] = *(const short8*)&As[(wr + i * 16 + c) * 32 + q * 8];
#pragma unroll
    for (int j = 0; j < 4; ++j)
      bv[j] = *(const short8*)&Bs[(wc + j * 16 + c) * 32 + q * 8];
#pragma unroll
    for (int i = 0; i < 4; ++i)
#pragma unroll
      for (int j = 0; j < 4; ++j)
        acc[i][j] = __builtin_amdgcn_mfma_f32_16x16x32_bf16(
            av[i], bv[j], acc[i][j], 0, 0, 0);
    __syncthreads();
  }

  // row = output V-channel (h*64+d), col = b*4096 + l
#pragma unroll
  for (int i = 0; i < 4; ++i)
#pragma unroll
    for (int j = 0; j < 4; ++j)
#pragma unroll
      for (int r = 0; r < 4; ++r) {
        const int row = row0 + wr + i * 16 + q * 4 + r;
        const int col = col0 + wc + j * 16 + c;
        const int bq = col >> 12, l = col & 4095;
        const int h = row >> 6, d = row & 63;
        VT[((size_t)((bq * 16 + h) * 64 + d)) * (size_t)kL + l] =
            f2bf(acc[i][j][r]);
      }
}

// ---------------------------------------------------------------------------
// Wo projection GEMM (r8 single-buffer), bf16 row-major out (Yb).
// ---------------------------------------------------------------------------
__global__ __launch_bounds__(256) void gemm_wo_mfma(
    const unsigned short* __restrict__ A, const unsigned short* __restrict__ BT,
    unsigned short* __restrict__ Yb)
{
  __shared__ unsigned short As[128 * 32];
  __shared__ unsigned short Bs[128 * 32];
  const int tid = threadIdx.x, lane = tid & 63, w = tid >> 6;
  const int q = lane >> 4, c = lane & 15;
  const int wr = (w >> 1) * 64, wc = (w & 1) * 64;
  int bx, by; xcd_swizzle(bx, by);
  const int row0 = by * 128, col0 = bx * 128;
  const int lrow = lane >> 2, lcol = (lane & 3) * 8;

  f32x4 acc[4][4];
#pragma unroll
  for (int i = 0; i < 4; ++i)
#pragma unroll
    for (int j = 0; j < 4; ++j) acc[i][j] = (f32x4)0.f;

  for (int k0 = 0; k0 < kD; k0 += 32) {
#pragma unroll
    for (int i = 0; i < 2; ++i) {
      const int r0 = w * 32 + i * 16;
      gload_lds16(&A[(size_t)(row0 + r0 + lrow) * kD + k0 + lcol], &As[r0 * 32]);
      gload_lds16(&BT[(size_t)(col0 + r0 + lrow) * kD + k0 + lcol], &Bs[r0 * 32]);
    }
    __syncthreads();
    short8 av[4], bv[4];
#pragma unroll
    for (int i = 0; i < 4; ++i)
      av[i] = *(const short8*)&As[(wr + i * 16 + c) * 32 + q * 8];
#pragma unroll
    for (int j = 0; j < 4; ++j)
      bv[j] = *(const short8*)&Bs[(wc + j * 16 + c) * 32 + q * 8];
#pragma unroll
    for (int i = 0; i < 4; ++i)
#pragma unroll
      for (int j = 0; j < 4; ++j)
        acc[i][j] = __builtin_amdgcn_mfma_f32_16x16x32_bf16(
            av[i], bv[j], acc[i][j], 0, 0, 0);
    __syncthreads();
  }

#pragma unroll
  for (int i = 0; i < 4; ++i)
#pragma unroll
    for (int j = 0; j < 4; ++j)
#pragma unroll
      for (int r = 0; r < 4; ++r) {
        const int row = row0 + wr + i * 16 + q * 4 + r;
        const int col = col0 + wc + j * 16 + c;
        Yb[(size_t)row * kD + col] = f2bf(acc[i][j][r]);
      }
}

// ---------------------------------------------------------------------------
// FAVOR-K via MFMA (r4/r8-proven TRANS=1 path): proj staged in LDS, Tbuf
// aliased onto Us. Stores KFT [bh][m][l] via 64-row LDS chunks. 56,832 B.
// ---------------------------------------------------------------------------
__global__ __launch_bounds__(256) void favor_k_mfma(
    const unsigned short* __restrict__ U, const unsigned short* __restrict__ projb,
    unsigned short* __restrict__ F)
{
  __shared__ unsigned short Us[128 * 72];    // 18.4 KB; reused as Tbuf later
  __shared__ unsigned short Ps[256 * 72];    // 36.9 KB, proj head, pad 72
  __shared__ float diagp[256];
  __shared__ float diag[128];
  unsigned short* Tbuf = Us;                 // alias: 64*136 = 8704 <= 9216
  const int bh = blockIdx.x, b = bh >> 4, h = bh & 15;
  const int l0 = blockIdx.y * 128;
  const int tid = threadIdx.x, lane = tid & 63, w = tid >> 6;
  const int q = lane >> 4, c = lane & 15;
  const int wr = w * 32;

#pragma unroll
  for (int it = 0; it < 4; ++it) {
    int idx = it * 256 + tid;
    int row = idx >> 3, col8 = idx & 7;
    *(uint4*)&Us[row * 72 + col8 * 8] =
        *(const uint4*)&U[((size_t)(b * kL + l0 + row)) * kD + h * kDH + col8 * 8];
  }
#pragma unroll
  for (int it = 0; it < 8; ++it) {
    int idx = it * 256 + tid;
    int row = idx >> 3, col8 = idx & 7;
    *(uint4*)&Ps[row * 72 + col8 * 8] =
        *(const uint4*)&projb[((size_t)(h * kM + row)) * kDH + col8 * 8];
  }
  __syncthreads();

  {
    int row = tid & 127, half = tid >> 7;
    const unsigned short* ur = &Us[row * 72 + half * 32];
    float s = 0.f;
#pragma unroll
    for (int d8 = 0; d8 < 4; ++d8) {
      uint4 raw = *(const uint4*)&ur[d8 * 8];
      const unsigned short* us = (const unsigned short*)&raw;
#pragma unroll
      for (int j = 0; j < 8; ++j) { float v = bf2f(us[j]); s = fmaf(v, v, s); }
    }
    diagp[half * 128 + row] = s;
  }

  f32x4 acc[2][16];
#pragma unroll
  for (int i = 0; i < 2; ++i)
#pragma unroll
    for (int j = 0; j < 16; ++j) acc[i][j] = (f32x4)0.f;

#pragma unroll
  for (int ks = 0; ks < 2; ++ks) {
    short8 av[2];
#pragma unroll
    for (int i = 0; i < 2; ++i)
      av[i] = *(const short8*)&Us[(wr + i * 16 + c) * 72 + ks * 32 + q * 8];
#pragma unroll
    for (int jb = 0; jb < 2; ++jb) {
      short8 bv[8];
#pragma unroll
      for (int jl = 0; jl < 8; ++jl)
        bv[jl] = *(const short8*)&Ps[((jb * 8 + jl) * 16 + c) * 72 + ks * 32 + q * 8];
#pragma unroll
      for (int jl = 0; jl < 8; ++jl)
#pragma unroll
        for (int i = 0; i < 2; ++i)
          acc[i][jb * 8 + jl] = __builtin_amdgcn_mfma_f32_16x16x32_bf16(
              av[i], bv[jl], acc[i][jb * 8 + jl], 0, 0, 0);
    }
  }

  __syncthreads();   // all Us reads complete (required: Tbuf aliases Us)
  if (tid < 128) diag[tid] = 0.5f * (diagp[tid] + diagp[128 + tid]);
  __syncthreads();

#pragma unroll
  for (int i = 0; i < 2; ++i)
#pragma unroll
    for (int r = 0; r < 4; ++r) {
      const int lrow = wr + i * 16 + q * 4 + r;
      float mx = -3.4e38f;
#pragma unroll
      for (int j = 0; j < 16; ++j) mx = fmaxf(mx, acc[i][j][r]);
      mx = fmaxf(mx, __shfl_xor(mx, 1, 64));
      mx = fmaxf(mx, __shfl_xor(mx, 2, 64));
      mx = fmaxf(mx, __shfl_xor(mx, 4, 64));
      mx = fmaxf(mx, __shfl_xor(mx, 8, 64));
      const float base = diag[lrow] + mx;
#pragma unroll
      for (int j = 0; j < 16; ++j)
        acc[i][j][r] = __expf(acc[i][j][r] - base) * kInvSqrtM;
    }

  // LDS-transpose 64-m chunks, store KFT[bh*256 + m][l0..l0+128).
#pragma unroll
  for (int mc = 0; mc < 4; ++mc) {
    __syncthreads();
#pragma unroll
    for (int jl = 0; jl < 4; ++jl) {
      const int jj = mc * 4 + jl;
#pragma unroll
      for (int i = 0; i < 2; ++i) {
        ushort4 o;
        o.x = f2bf(acc[i][jj][0]); o.y = f2bf(acc[i][jj][1]);
        o.z = f2bf(acc[i][jj][2]); o.w = f2bf(acc[i][jj][3]);
        *(ushort4*)&Tbuf[(jl * 16 + c) * 136 + wr + i * 16 + q * 4] = o;
      }
    }
    __syncthreads();
#pragma unroll
    for (int it = 0; it < 4; ++it) {       // 1024 uint4 = 64 rows x 16
      int idx = it * 256 + tid;
      int row = idx >> 4, col8 = idx & 15;
      *(uint4*)&F[((size_t)(bh * kM + mc * 64 + row)) * (size_t)kL +
                  l0 + col8 * 8] = *(const uint4*)&Tbuf[row * 136 + col8 * 8];
    }
  }
}

// ---------------------------------------------------------------------------
// FUSED FAVOR-Q + attention read-out, occupancy-tuned (r10 win + LDS diet).
// Changes vs r10: (a) proj staged in 2 halves of [128][72] (Phase A LDS
// 55.3 -> 36.9 KB); (b) Phase B stages only the 64 real kv rows (no zero
// pad tile); denominator computed via VALU+shfl from in-register qf and the
// ksum row (512 B in LDS). Total static LDS 46,080 B -> 3 blocks/CU (was 2).
// ---------------------------------------------------------------------------
__global__ __launch_bounds__(256) void fused_qf_attn(
    const unsigned short* __restrict__ U, const unsigned short* __restrict__ projb,
    const unsigned short* __restrict__ KVT, unsigned short* __restrict__ ATTN)
{
  __shared__ unsigned short SA[22016];   // 44,032 B union (see below)
  __shared__ float diagp[256];
  __shared__ float diag[128];
  __shared__ unsigned short ksumS[256];
  unsigned short* Us  = SA;              // [128][72] = 9216   (phase A)
  unsigned short* Ps2 = SA + 9216;       // [128][72] = 9216   (phase A, half)
  unsigned short* kvs = SA;              // [64][264] = 16896  (phase B)
  unsigned short* qs  = SA + 16896;      // [128][40] = 5120   (phase B)
  const int bh = blockIdx.x, b = bh >> 4, h = bh & 15;
  const int l0 = blockIdx.y * 128;
  const int tid = threadIdx.x, lane = tid & 63, w = tid >> 6;
  const int q = lane >> 4, c = lane & 15;
  const int wr = w * 32;

  // --- Phase A: dash + exp, proj staged in two 128-row halves ---
#pragma unroll
  for (int it = 0; it < 4; ++it) {
    int idx = it * 256 + tid;
    int row = idx >> 3, col8 = idx & 7;
    *(uint4*)&Us[row * 72 + col8 * 8] =
        *(const uint4*)&U[((size_t)(b * kL + l0 + row)) * kD + h * kDH + col8 * 8];
  }
#pragma unroll
  for (int it = 0; it < 4; ++it) {       // proj half 0: rows 0..127
    int idx = it * 256 + tid;
    int row = idx >> 3, col8 = idx & 7;
    *(uint4*)&Ps2[row * 72 + col8 * 8] =
        *(const uint4*)&projb[((size_t)(h * kM + row)) * kDH + col8 * 8];
  }
  __syncthreads();

  {
    int row = tid & 127, half = tid >> 7;
    const unsigned short* ur = &Us[row * 72 + half * 32];
    float s = 0.f;
#pragma unroll
    for (int d8 = 0; d8 < 4; ++d8) {
      uint4 raw = *(const uint4*)&ur[d8 * 8];
      const unsigned short* us = (const unsigned short*)&raw;
#pragma unroll
      for (int j = 0; j < 8; ++j) { float v = bf2f(us[j]); s = fmaf(v, v, s); }
    }
    diagp[half * 128 + row] = s;
  }

  f32x4 acc[2][16];
#pragma unroll
  for (int i = 0; i < 2; ++i)
#pragma unroll
    for (int j = 0; j < 16; ++j) acc[i][j] = (f32x4)0.f;

#pragma unroll
  for (int half = 0; half < 2; ++half) {
    if (half == 1) {
      __syncthreads();   // prior Ps2 reads done
#pragma unroll
      for (int it = 0; it < 4; ++it) {   // proj half 1: rows 128..255
        int idx = it * 256 + tid;
        int row = idx >> 3, col8 = idx & 7;
        *(uint4*)&Ps2[row * 72 + col8 * 8] =
            *(const uint4*)&projb[((size_t)(h * kM + 128 + row)) * kDH + col8 * 8];
      }
      __syncthreads();
    }
#pragma unroll
    for (int ks = 0; ks < 2; ++ks) {
      short8 av[2];
#pragma unroll
      for (int i = 0; i < 2; ++i)
        av[i] = *(const short8*)&Us[(wr + i * 16 + c) * 72 + ks * 32 + q * 8];
      short8 bv[8];
#pragma unroll
      for (int jl = 0; jl < 8; ++jl)
        bv[jl] = *(const short8*)&Ps2[(jl * 16 + c) * 72 + ks * 32 + q * 8];
#pragma unroll
      for (int jl = 0; jl < 8; ++jl)
#pragma unroll
        for (int i = 0; i < 2; ++i)
          acc[i][half * 8 + jl] = __builtin_amdgcn_mfma_f32_16x16x32_bf16(
              av[i], bv[jl], acc[i][half * 8 + jl], 0, 0, 0);
    }
  }

  __syncthreads();   // all Us/Ps2 reads complete; alias region reusable
  if (tid < 128) diag[tid] = 0.5f * (diagp[tid] + diagp[128 + tid]);
  // stage kvs: 64 rows x 256 cols = 2048 uint4, 8 per thread
#pragma unroll
  for (int it = 0; it < 8; ++it) {
    int idx = it * 256 + tid;
    int row = idx >> 5, col8 = (idx & 31) * 8;
    *(uint4*)&kvs[row * 264 + col8] =
        *(const uint4*)&KVT[(size_t)bh * (80 * kM) + row * kM + col8];
  }
  // stage ksum row (KVT row 64): 32 uint4
  if (tid < 32)
    *(uint4*)&ksumS[tid * 8] =
        *(const uint4*)&KVT[(size_t)bh * (80 * kM) + 64 * kM + tid * 8];
  __syncthreads();   // diag + kvs + ksum ready

  // exp epilogue in registers: acc <- exp(dash - diag - rowmax) * M^-0.5
#pragma unroll
  for (int i = 0; i < 2; ++i)
#pragma unroll
    for (int r = 0; r < 4; ++r) {
      const int lrow = wr + i * 16 + q * 4 + r;
      float mx = -3.4e38f;
#pragma unroll
      for (int j = 0; j < 16; ++j) mx = fmaxf(mx, acc[i][j][r]);
      mx = fmaxf(mx, __shfl_xor(mx, 1, 64));
      mx = fmaxf(mx, __shfl_xor(mx, 2, 64));
      mx = fmaxf(mx, __shfl_xor(mx, 4, 64));
      mx = fmaxf(mx, __shfl_xor(mx, 8, 64));
      const float base = diag[lrow] + mx;
#pragma unroll
      for (int j = 0; j < 16; ++j)
        acc[i][j][r] = __expf(acc[i][j][r] - base) * kInvSqrtM;
    }

  // denominator via VALU + shfl: den[row] = sum_m qf[row][m] * ksum[m]
  float z_[2][4];
#pragma unroll
  for (int i = 0; i < 2; ++i)
#pragma unroll
    for (int r = 0; r < 4; ++r) {
      float d = 0.f;
#pragma unroll
      for (int j = 0; j < 16; ++j)
        d = fmaf(acc[i][j][r], bf2f(ksumS[j * 16 + c]), d);
      d += __shfl_xor(d, 1, 64);
      d += __shfl_xor(d, 2, 64);
      d += __shfl_xor(d, 4, 64);
      d += __shfl_xor(d, 8, 64);
      z_[i][r] = 1.f / (d + kEps);
    }

  // --- Phase B: attn MFMA over 8 m-chunks of 32, 4 real n-tiles ---
  f32x4 acc2[2][4];
#pragma unroll
  for (int i = 0; i < 2; ++i)
#pragma unroll
    for (int j = 0; j < 4; ++j) acc2[i][j] = (f32x4)0.f;

#pragma unroll
  for (int kk = 0; kk < 8; ++kk) {
#pragma unroll
    for (int i = 0; i < 2; ++i)
#pragma unroll
      for (int jj2 = 0; jj2 < 2; ++jj2) {
        const int jj = kk * 2 + jj2;
#pragma unroll
        for (int r = 0; r < 4; ++r)
          qs[(wr + i * 16 + q * 4 + r) * 40 + jj2 * 16 + c] =
              f2bf(acc[i][jj][r]);
      }
    __syncthreads();
    short8 bv2[4];
#pragma unroll
    for (int j = 0; j < 4; ++j)
      bv2[j] = *(const short8*)&kvs[(j * 16 + c) * 264 + kk * 32 + q * 8];
#pragma unroll
    for (int i = 0; i < 2; ++i) {
      short8 av2 = *(const short8*)&qs[(w * 32 + i * 16 + c) * 40 + q * 8];
#pragma unroll
      for (int j = 0; j < 4; ++j)
        acc2[i][j] = __builtin_amdgcn_mfma_f32_16x16x32_bf16(
            av2, bv2[j], acc2[i][j], 0, 0, 0);
    }
    __syncthreads();   // qs consumed; next chunk may overwrite
  }

  // epilogue: scale by 1/den, write ATTN
#pragma unroll
  for (int i = 0; i < 2; ++i)
#pragma unroll
    for (int r = 0; r < 4; ++r) {
      const int row = l0 + w * 32 + i * 16 + q * 4 + r;
      const size_t base = ((size_t)(b * kL + row)) * kD + h * kDH;
#pragma unroll
      for (int j = 0; j < 4; ++j)
        ATTN[base + j * 16 + c] = f2bf(acc2[i][j][r] * z_[i][r]);
    }
}

// ---------------------------------------------------------------------------
// kv via MFMA, r8-proven m97-style async staging: per (bh, mtile, split):
// C[128 m][64 d] = KFT tile @ VT tile^T over 512 l. ksum from A-fragments.
// ---------------------------------------------------------------------------
__global__ __launch_bounds__(256) void kv_mfma(
    const unsigned short* __restrict__ KFT, const unsigned short* __restrict__ VT,
    float* __restrict__ KVP, float* __restrict__ KSP)
{
  __shared__ unsigned short As[128 * 32];   // 8 KB
  __shared__ unsigned short Bs[64 * 32];    // 4 KB
  const int bh = blockIdx.x, mtile = blockIdx.y, split = blockIdx.z;
  const int tid = threadIdx.x, lane = tid & 63, w = tid >> 6;
  const int q = lane >> 4, c = lane & 15;
  const int l0 = split * 512;
  const unsigned short* Abase = KFT + ((size_t)(bh * kM + mtile * 128)) * kL + l0;
  const unsigned short* Bbase = VT + ((size_t)(bh * kDH)) * kL + l0;
  const int lrow = lane >> 2, lcol = (lane & 3) * 8;

  f32x4 acc[2][4];
#pragma unroll
  for (int i = 0; i < 2; ++i)
#pragma unroll
    for (int j = 0; j < 4; ++j) acc[i][j] = (f32x4)0.f;
  float ksr[2] = {0.f, 0.f};

  for (int k0 = 0; k0 < 512; k0 += 32) {
#pragma unroll
    for (int i = 0; i < 2; ++i) {
      const int r0 = w * 32 + i * 16;
      gload_lds16(&Abase[(size_t)(r0 + lrow) * kL + k0 + lcol], &As[r0 * 32]);
    }
    gload_lds16(&Bbase[(size_t)(w * 16 + lrow) * kL + k0 + lcol], &Bs[w * 16 * 32]);
    __syncthreads();
    short8 av[2], bv[4];
#pragma unroll
    for (int i = 0; i < 2; ++i) {
      av[i] = *(const short8*)&As[(w * 32 + i * 16 + c) * 32 + q * 8];
#pragma unroll
      for (int e = 0; e < 8; ++e) ksr[i] += bf2f((unsigned short)av[i][e]);
    }
#pragma unroll
    for (int j = 0; j < 4; ++j)
      bv[j] = *(const short8*)&Bs[(j * 16 + c) * 32 + q * 8];
#pragma unroll
    for (int i = 0; i < 2; ++i)
#pragma unroll
      for (int j = 0; j < 4; ++j)
        acc[i][j] = __builtin_amdgcn_mfma_f32_16x16x32_bf16(
            av[i], bv[j], acc[i][j], 0, 0, 0);
    __syncthreads();
  }

  const int blk = (bh * 2 + mtile) * 8 + split;
  float* op = KVP + (size_t)blk * (128 * 64);
#pragma unroll
  for (int i = 0; i < 2; ++i)
#pragma unroll
    for (int j = 0; j < 4; ++j)
#pragma unroll
      for (int r = 0; r < 4; ++r)
        op[(w * 32 + i * 16 + q * 4 + r) * 64 + j * 16 + c] = acc[i][j][r];

#pragma unroll
  for (int i = 0; i < 2; ++i) {
    float s = ksr[i];
    s += __shfl_xor(s, 16, 64);
    s += __shfl_xor(s, 32, 64);
    if (q == 0) KSP[blk * 128 + w * 32 + i * 16 + c] = s;
  }
}

// Reduce 8 splits -> KVT' bf16 [bh][80][256]: rows 0..63 = kv^T[d][m],
// row 64 = ksum[m], rows 65..79 = 0 (pad rows kept for layout compat).
__global__ __launch_bounds__(256) void kv_reduce_kernel(
    const float* __restrict__ KVP, const float* __restrict__ KSP,
    unsigned short* __restrict__ KVT)
{
  const int blk = blockIdx.x;            // 32*80
  const int bh = blk / 80, n = blk - bh * 80;
  const int t = threadIdx.x;             // m
  const int mt = t >> 7, ml = t & 127;
  float s = 0.f;
  if (n < 64) {
#pragma unroll
    for (int sp = 0; sp < 8; ++sp)
      s += KVP[((size_t)((bh * 2 + mt) * 8 + sp)) * (128 * 64) + ml * 64 + n];
  } else if (n == 64) {
#pragma unroll
    for (int sp = 0; sp < 8; ++sp)
      s += KSP[((bh * 2 + mt) * 8 + sp) * 128 + ml];
  }
  KVT[(size_t)bh * (80 * kM) + n * kM + t] = f2bf(s);
}

// ---------------------------------------------------------------------------
// GELU (exact) + LayerNorm + 2x nearest-neighbor duplicate write.
// Reads Y as bf16 (written by gemm_wo) — halves the Y round trip.
// ---------------------------------------------------------------------------
__global__ __launch_bounds__(256) void gelu_ln_kernel(
    const unsigned short* __restrict__ Yb, const float* __restrict__ lng,
    const float* __restrict__ lnb, float* __restrict__ OUT)
{
  __shared__ float r1[4], r2[4];
  const int n = blockIdx.x;
  const int tid = threadIdx.x, lane = tid & 63, w = tid >> 6;

  ushort4 yv = ((const ushort4*)(Yb + (size_t)n * kD))[tid];
  float y0 = bf2f(yv.x), y1 = bf2f(yv.y), y2 = bf2f(yv.z), y3 = bf2f(yv.w);
  float g0 = 0.5f * y0 * (1.f + erff(y0 * 0.70710678118654752f));
  float g1 = 0.5f * y1 * (1.f + erff(y1 * 0.70710678118654752f));
  float g2 = 0.5f * y2 * (1.f + erff(y2 * 0.70710678118654752f));
  float g3 = 0.5f * y3 * (1.f + erff(y3 * 0.70710678118654752f));

  float s  = (g0 + g1) + (g2 + g3);
  float ss = (g0 * g0 + g1 * g1) + (g2 * g2 + g3 * g3);
#pragma unroll
  for (int off = 32; off; off >>= 1) {
    s  += __shfl_xor(s, off, 64);
    ss += __shfl_xor(ss, off, 64);
  }
  if (lane == 0) { r1[w] = s; r2[w] = ss; }
  __syncthreads();
  s  = (r1[0] + r1[1]) + (r1[2] + r1[3]);
  ss = (r2[0] + r2[1]) + (r2[2] + r2[3]);
  float mu  = s * (1.f / (float)kD);
  float var = ss * (1.f / (float)kD) - mu * mu;
  float inv = rsqrtf(var + kLnEps);

  float4 gg = ((const float4*)lng)[tid];
  float4 bb = ((const float4*)lnb)[tid];
  float4 o;
  o.x = (g0 - mu) * inv * gg.x + bb.x;
  o.y = (g1 - mu) * inv * gg.y + bb.y;
  o.z = (g2 - mu) * inv * gg.z + bb.z;
  o.w = (g3 - mu) * inv * gg.w + bb.w;

  const int b = n >> 12, l = n & 4095;
  const int cc = tid * 4;
  size_t base = ((size_t)(b * 8192 + 2 * l)) * kD + cc;
  *(float4*)(OUT + base)      = o;
  *(float4*)(OUT + base + kD) = o;
}

// ---------------------------------------------------------------------------
extern "C" void kernel_launch(void* const* d_in, const int* in_sizes, int n_in,
                              void* d_out, int out_size, void* d_ws, size_t ws_size,
                              hipStream_t stream)
{
  (void)in_sizes; (void)n_in; (void)out_size; (void)ws_size;
  const float* x    = (const float*)d_in[0];
  const float* Wq   = (const float*)d_in[1];
  const float* Wk   = (const float*)d_in[2];
  const float* Wv   = (const float*)d_in[3];
  const float* Wo   = (const float*)d_in[4];
  const float* proj = (const float*)d_in[5];
  const float* lng  = (const float*)d_in[6];
  const float* lnb  = (const float*)d_in[7];
  float* out = (float*)d_out;

  // Workspace layout (MB offsets):
  //  0   xb    bf16 [8192,1024]
  //  16  WqkvT bf16 [3072,1024] (Wq/Wk/Wv transposed, stacked)
  //  22  WoT   bf16 [1024,1024] transposed
  //  24  Qb    bf16 [8192,1024] (live until fused_qf_attn)
  //  40  Kb    bf16 (consumed by favor_k; reused as ATTN bf16)
  //  56  VT    bf16 [32 bh][64 d][4096 l]
  //  72  KVP   f32 [512][128*64] 16 MB (dead after kv_reduce; Yb reuses)
  //  136 KFT   bf16 [32 bh][256 m][4096 l]
  //  200 KSP   f32 [512][128]
  //  201 KVT   bf16 [32,80,256]
  //  203 projb bf16 [16,256,64]
  char* ws = (char*)d_ws;
  const size_t MB = 1024 * 1024;
  unsigned short* xb    = (unsigned short*)(ws);
  unsigned short* WqkvT = (unsigned short*)(ws + 16 * MB);
  unsigned short* WoT   = (unsigned short*)(ws + 22 * MB);
  unsigned short* Qb    = (unsigned short*)(ws + 24 * MB);
  unsigned short* Kb    = (unsigned short*)(ws + 40 * MB);
  unsigned short* VT    = (unsigned short*)(ws + 56 * MB);
  float* KVP            = (float*)(ws + 72 * MB);
  unsigned short* KFT   = (unsigned short*)(ws + 136 * MB);
  float* KSP            = (float*)(ws + 200 * MB);
  unsigned short* KVT   = (unsigned short*)(ws + 201 * MB);
  unsigned short* projb = (unsigned short*)(ws + 203 * MB);
  unsigned short* ATTN  = Kb;                       // after favor_k consumed Kb
  unsigned short* Yb    = (unsigned short*)(ws + 72 * MB);  // after KVP dead
  unsigned short* WvT   = WqkvT + (size_t)2 * kD * kD;

  // 1) casts + weight transposes (one launch)
  cast_bf16_kernel<<<(kN * kD) / 1024, 256, 0, stream>>>(x, xb);
  cast_bf16_kernel<<<(kH * kM * kDH) / 1024, 256, 0, stream>>>(proj, projb);
  transpose_cast4_kernel<<<dim3(32, 32, 4), 256, 0, stream>>>(
      Wq, Wk, Wv, Wo, WqkvT, WoT);

  // 2) projections: merged Q+K; V^T direct via swapped-operand GEMM
  gemm_qk_mfma<<<dim3(16, 64), 256, 0, stream>>>(xb, WqkvT, Qb, Kb);
  gemm_vt_mfma<<<dim3(8, 64), 256, 0, stream>>>(WvT, xb, VT);

  // 3) FAVOR-K (stored transposed), then kv / ksum, reduce to KVT'
  favor_k_mfma<<<dim3(32, 32), 256, 0, stream>>>(Kb, projb, KFT);
  kv_mfma<<<dim3(32, 2, 8), 256, 0, stream>>>(KFT, VT, KVP, KSP);
  kv_reduce_kernel<<<32 * 80, 256, 0, stream>>>(KVP, KSP, KVT);

  // 4) fused FAVOR-Q + attention read-out -> bf16 ATTN (QF eliminated)
  fused_qf_attn<<<dim3(32, 32), 256, 0, stream>>>(Qb, projb, KVT, ATTN);

  // 5) output projection (bf16 out)
  gemm_wo_mfma<<<dim3(8, 64), 256, 0, stream>>>(ATTN, WoT, Yb);

  // 6) GELU + LayerNorm + 2x duplicate write
  gelu_ln_kernel<<<kN, 256, 0, stream>>>(Yb, lng, lnb, out);
}

// Round 12
// 329.089 us; speedup vs baseline: 1.0370x; 1.0370x over previous
//
#include <hip/hip_runtime.h>

// Problem constants (fixed by the reference).
static constexpr int kB  = 2;
static constexpr int kL  = 4096;   // source sequence length
static constexpr int kD  = 1024;
static constexpr int kH  = 16;
static constexpr int kDH = 64;
static constexpr int kM  = 256;
static constexpr int kN  = kB * kL;              // 8192 deduplicated rows
static constexpr float kScale    = 0.35355339059327373f;  // DH^-0.25
static constexpr float kInvSqrtM = 0.0625f;               // M^-0.5
static constexpr float kEps   = 1e-6f;
static constexpr float kLnEps = 1e-5f;

typedef __attribute__((ext_vector_type(8))) short short8;   // 8 bf16 (4 VGPRs)
typedef __attribute__((ext_vector_type(4))) float f32x4;

__device__ __forceinline__ float bf2f(unsigned short h) {
  union { unsigned int u; float f; } c;
  c.u = ((unsigned int)h) << 16;
  return c.f;
}
__device__ __forceinline__ unsigned short f2bf(float f) {
  union { float f; unsigned int u; } c;
  c.f = f;
  unsigned int u = c.u;
  u += 0x7fffu + ((u >> 16) & 1u);   // round-to-nearest-even
  return (unsigned short)(u >> 16);
}

// async global->LDS, 16 B per lane; LDS dest = wave-uniform base + lane*16.
__device__ __forceinline__ void gload_lds16(const unsigned short* g,
                                            unsigned short* l) {
  __builtin_amdgcn_global_load_lds(
      (const __attribute__((address_space(1))) unsigned int*)g,
      (__attribute__((address_space(3))) unsigned int*)l, 16, 0, 0);
}

// Bijective XCD-chunked block remap (nwg must be a multiple of 8).
__device__ __forceinline__ void xcd_swizzle(int& bx, int& by) {
  const int nwg = gridDim.x * gridDim.y;
  const int bid = blockIdx.x + gridDim.x * blockIdx.y;
  const int cpx = nwg >> 3;
  const int sb  = (bid & 7) * cpx + (bid >> 3);
  bx = sb % gridDim.x;
  by = sb / gridDim.x;
}

// ---------------------------------------------------------------------------
// casts
// ---------------------------------------------------------------------------
__global__ __launch_bounds__(256) void cast_bf16_kernel(
    const float* __restrict__ in, unsigned short* __restrict__ out)
{
  const int i = blockIdx.x * 256 + threadIdx.x;
  float4 v = ((const float4*)in)[i];
  ushort4 o;
  o.x = f2bf(v.x); o.y = f2bf(v.y); o.z = f2bf(v.z); o.w = f2bf(v.w);
  ((ushort4*)out)[i] = o;
}

// All four weight transposes in one launch. z in {0,1,2}: Wq/Wk/Wv into
// WqkvT[3072][1024] at row offset z*1024; z==3: Wo into WoT.
__global__ __launch_bounds__(256) void transpose_cast4_kernel(
    const float* __restrict__ W0, const float* __restrict__ W1,
    const float* __restrict__ W2, const float* __restrict__ W3,
    unsigned short* __restrict__ WqkvT, unsigned short* __restrict__ WoT)
{
  __shared__ float tile[32][33];
  const int z = blockIdx.z;
  const float* W = (z == 0) ? W0 : (z == 1) ? W1 : (z == 2) ? W2 : W3;
  unsigned short* WT = (z < 3) ? (WqkvT + (size_t)z * kD * kD) : WoT;
  const int n0 = blockIdx.x * 32, k0 = blockIdx.y * 32;
  const int t = threadIdx.x, kk = t >> 5, nn = t & 31;
#pragma unroll
  for (int i = 0; i < 4; ++i)
    tile[kk + i * 8][nn] = W[(size_t)(k0 + kk + i * 8) * kD + n0 + nn];
  __syncthreads();
#pragma unroll
  for (int i = 0; i < 4; ++i)
    WT[(size_t)(n0 + kk + i * 8) * kD + k0 + nn] = f2bf(tile[nn][kk + i * 8]);
}

// ---------------------------------------------------------------------------
// BK=64 K-loop GEMM body (shared by the 3 weight GEMMs): 16 K-steps (half
// the barriers of BK=32). 128 B LDS rows would be a same-bank hazard, so
// the global SOURCE is pre-swizzled per-lane (chunk ^= row&7), LDS dest
// stays linear (gload_lds16 requirement), and fragment reads apply the
// same XOR — uniform 8-lanes-per-bank-set = structural minimum.
// ---------------------------------------------------------------------------
#define GEMM_BK64_BODY(Aptr, Bptr, arow0, bcol0)                              \
  const int lrow = lane >> 3;                                                 \
  const int lcol = ((lane & 7) ^ lrow) * 8; /* swizzled global chunk */       \
  f32x4 acc[4][4];                                                            \
  _Pragma("unroll")                                                           \
  for (int i = 0; i < 4; ++i)                                                 \
    _Pragma("unroll")                                                         \
    for (int j = 0; j < 4; ++j) acc[i][j] = (f32x4)0.f;                       \
  for (int k0 = 0; k0 < kD; k0 += 64) {                                       \
    _Pragma("unroll")                                                         \
    for (int i = 0; i < 4; ++i) {                                             \
      const int r0 = w * 32 + i * 8;                                          \
      gload_lds16(&Aptr[(size_t)(arow0 + r0 + lrow) * kD + k0 + lcol],        \
                  &As[r0 * 64]);                                              \
      gload_lds16(&Bptr[(size_t)(bcol0 + r0 + lrow) * kD + k0 + lcol],        \
                  &Bs[r0 * 64]);                                              \
    }                                                                         \
    __syncthreads();                                                          \
    _Pragma("unroll")                                                         \
    for (int ks = 0; ks < 2; ++ks) {                                          \
      short8 av[4], bv[4];                                                    \
      const int ch = ks * 4 + q;                                              \
      _Pragma("unroll")                                                       \
      for (int i = 0; i < 4; ++i)                                             \
        av[i] = *(const short8*)&As[(wr + i * 16 + c) * 64 +                  \
                                    ((ch ^ (c & 7)) * 8)];                    \
      _Pragma("unroll")                                                       \
      for (int j = 0; j < 4; ++j)                                             \
        bv[j] = *(const short8*)&Bs[(wc + j * 16 + c) * 64 +                  \
                                    ((ch ^ (c & 7)) * 8)];                    \
      _Pragma("unroll")                                                       \
      for (int i = 0; i < 4; ++i)                                             \
        _Pragma("unroll")                                                     \
        for (int j = 0; j < 4; ++j)                                           \
          acc[i][j] = __builtin_amdgcn_mfma_f32_16x16x32_bf16(                \
              av[i], bv[j], acc[i][j], 0, 0, 0);                              \
    }                                                                         \
    __syncthreads();                                                          \
  }

// ---------------------------------------------------------------------------
// Merged Q+K projection GEMM (BK=64 swizzled, XCD-swizzled).
// ---------------------------------------------------------------------------
__global__ __launch_bounds__(256) void gemm_qk_mfma(
    const unsigned short* __restrict__ A, const unsigned short* __restrict__ BT,
    unsigned short* __restrict__ Qb, unsigned short* __restrict__ Kb)
{
  __shared__ unsigned short As[128 * 64];   // 16 KB
  __shared__ unsigned short Bs[128 * 64];   // 16 KB
  const int tid = threadIdx.x, lane = tid & 63, w = tid >> 6;
  const int q = lane >> 4, c = lane & 15;
  const int wr = (w >> 1) * 64, wc = (w & 1) * 64;
  int bx, by; xcd_swizzle(bx, by);
  const int row0 = by * 128, col0 = bx * 128;

  GEMM_BK64_BODY(A, BT, row0, col0)

  unsigned short* O = (col0 < 1024) ? Qb : Kb;
  const int cl0 = col0 & 1023;
#pragma unroll
  for (int i = 0; i < 4; ++i)
#pragma unroll
    for (int j = 0; j < 4; ++j)
#pragma unroll
      for (int r = 0; r < 4; ++r) {
        const int row = row0 + wr + i * 16 + q * 4 + r;
        const int col = cl0 + wc + j * 16 + c;
        O[(size_t)row * kD + col] = f2bf(kScale * acc[i][j][r]);
      }
}

// ---------------------------------------------------------------------------
// V^T projection GEMM via swapped operands (BK=64 swizzled).
// VT row-major natively -> plain coalesced bf16 stores, no transpose.
// ---------------------------------------------------------------------------
__global__ __launch_bounds__(256) void gemm_vt_mfma(
    const unsigned short* __restrict__ A, const unsigned short* __restrict__ BT,
    unsigned short* __restrict__ VT)
{
  __shared__ unsigned short As[128 * 64];
  __shared__ unsigned short Bs[128 * 64];
  const int tid = threadIdx.x, lane = tid & 63, w = tid >> 6;
  const int q = lane >> 4, c = lane & 15;
  const int wr = (w >> 1) * 64, wc = (w & 1) * 64;
  int bx, by; xcd_swizzle(bx, by);
  const int row0 = bx * 128, col0 = by * 128;   // rows = WvT (8), cols = l (64)

  GEMM_BK64_BODY(A, BT, row0, col0)

  // row = output V-channel (h*64+d), col = b*4096 + l
#pragma unroll
  for (int i = 0; i < 4; ++i)
#pragma unroll
    for (int j = 0; j < 4; ++j)
#pragma unroll
      for (int r = 0; r < 4; ++r) {
        const int row = row0 + wr + i * 16 + q * 4 + r;
        const int col = col0 + wc + j * 16 + c;
        const int bq = col >> 12, l = col & 4095;
        const int h = row >> 6, d = row & 63;
        VT[((size_t)((bq * 16 + h) * 64 + d)) * (size_t)kL + l] =
            f2bf(acc[i][j][r]);
      }
}

// ---------------------------------------------------------------------------
// Wo projection GEMM (BK=64 swizzled), bf16 row-major out (Yb).
// ---------------------------------------------------------------------------
__global__ __launch_bounds__(256) void gemm_wo_mfma(
    const unsigned short* __restrict__ A, const unsigned short* __restrict__ BT,
    unsigned short* __restrict__ Yb)
{
  __shared__ unsigned short As[128 * 64];
  __shared__ unsigned short Bs[128 * 64];
  const int tid = threadIdx.x, lane = tid & 63, w = tid >> 6;
  const int q = lane >> 4, c = lane & 15;
  const int wr = (w >> 1) * 64, wc = (w & 1) * 64;
  int bx, by; xcd_swizzle(bx, by);
  const int row0 = by * 128, col0 = bx * 128;

  GEMM_BK64_BODY(A, BT, row0, col0)

#pragma unroll
  for (int i = 0; i < 4; ++i)
#pragma unroll
    for (int j = 0; j < 4; ++j)
#pragma unroll
      for (int r = 0; r < 4; ++r) {
        const int row = row0 + wr + i * 16 + q * 4 + r;
        const int col = col0 + wc + j * 16 + c;
        Yb[(size_t)row * kD + col] = f2bf(acc[i][j][r]);
      }
}

// ---------------------------------------------------------------------------
// FAVOR-K via MFMA (r4/r8-proven TRANS=1 path): proj staged in LDS, Tbuf
// aliased onto Us. Stores KFT [bh][m][l] via 64-row LDS chunks. 56,832 B.
// ---------------------------------------------------------------------------
__global__ __launch_bounds__(256) void favor_k_mfma(
    const unsigned short* __restrict__ U, const unsigned short* __restrict__ projb,
    unsigned short* __restrict__ F)
{
  __shared__ unsigned short Us[128 * 72];    // 18.4 KB; reused as Tbuf later
  __shared__ unsigned short Ps[256 * 72];    // 36.9 KB, proj head, pad 72
  __shared__ float diagp[256];
  __shared__ float diag[128];
  unsigned short* Tbuf = Us;                 // alias: 64*136 = 8704 <= 9216
  const int bh = blockIdx.x, b = bh >> 4, h = bh & 15;
  const int l0 = blockIdx.y * 128;
  const int tid = threadIdx.x, lane = tid & 63, w = tid >> 6;
  const int q = lane >> 4, c = lane & 15;
  const int wr = w * 32;

#pragma unroll
  for (int it = 0; it < 4; ++it) {
    int idx = it * 256 + tid;
    int row = idx >> 3, col8 = idx & 7;
    *(uint4*)&Us[row * 72 + col8 * 8] =
        *(const uint4*)&U[((size_t)(b * kL + l0 + row)) * kD + h * kDH + col8 * 8];
  }
#pragma unroll
  for (int it = 0; it < 8; ++it) {
    int idx = it * 256 + tid;
    int row = idx >> 3, col8 = idx & 7;
    *(uint4*)&Ps[row * 72 + col8 * 8] =
        *(const uint4*)&projb[((size_t)(h * kM + row)) * kDH + col8 * 8];
  }
  __syncthreads();

  {
    int row = tid & 127, half = tid >> 7;
    const unsigned short* ur = &Us[row * 72 + half * 32];
    float s = 0.f;
#pragma unroll
    for (int d8 = 0; d8 < 4; ++d8) {
      uint4 raw = *(const uint4*)&ur[d8 * 8];
      const unsigned short* us = (const unsigned short*)&raw;
#pragma unroll
      for (int j = 0; j < 8; ++j) { float v = bf2f(us[j]); s = fmaf(v, v, s); }
    }
    diagp[half * 128 + row] = s;
  }

  f32x4 acc[2][16];
#pragma unroll
  for (int i = 0; i < 2; ++i)
#pragma unroll
    for (int j = 0; j < 16; ++j) acc[i][j] = (f32x4)0.f;

#pragma unroll
  for (int ks = 0; ks < 2; ++ks) {
    short8 av[2];
#pragma unroll
    for (int i = 0; i < 2; ++i)
      av[i] = *(const short8*)&Us[(wr + i * 16 + c) * 72 + ks * 32 + q * 8];
#pragma unroll
    for (int jb = 0; jb < 2; ++jb) {
      short8 bv[8];
#pragma unroll
      for (int jl = 0; jl < 8; ++jl)
        bv[jl] = *(const short8*)&Ps[((jb * 8 + jl) * 16 + c) * 72 + ks * 32 + q * 8];
#pragma unroll
      for (int jl = 0; jl < 8; ++jl)
#pragma unroll
        for (int i = 0; i < 2; ++i)
          acc[i][jb * 8 + jl] = __builtin_amdgcn_mfma_f32_16x16x32_bf16(
              av[i], bv[jl], acc[i][jb * 8 + jl], 0, 0, 0);
    }
  }

  __syncthreads();   // all Us reads complete (required: Tbuf aliases Us)
  if (tid < 128) diag[tid] = 0.5f * (diagp[tid] + diagp[128 + tid]);
  __syncthreads();

#pragma unroll
  for (int i = 0; i < 2; ++i)
#pragma unroll
    for (int r = 0; r < 4; ++r) {
      const int lrow = wr + i * 16 + q * 4 + r;
      float mx = -3.4e38f;
#pragma unroll
      for (int j = 0; j < 16; ++j) mx = fmaxf(mx, acc[i][j][r]);
      mx = fmaxf(mx, __shfl_xor(mx, 1, 64));
      mx = fmaxf(mx, __shfl_xor(mx, 2, 64));
      mx = fmaxf(mx, __shfl_xor(mx, 4, 64));
      mx = fmaxf(mx, __shfl_xor(mx, 8, 64));
      const float base = diag[lrow] + mx;
#pragma unroll
      for (int j = 0; j < 16; ++j)
        acc[i][j][r] = __expf(acc[i][j][r] - base) * kInvSqrtM;
    }

  // LDS-transpose 64-m chunks, store KFT[bh*256 + m][l0..l0+128).
#pragma unroll
  for (int mc = 0; mc < 4; ++mc) {
    __syncthreads();
#pragma unroll
    for (int jl = 0; jl < 4; ++jl) {
      const int jj = mc * 4 + jl;
#pragma unroll
      for (int i = 0; i < 2; ++i) {
        ushort4 o;
        o.x = f2bf(acc[i][jj][0]); o.y = f2bf(acc[i][jj][1]);
        o.z = f2bf(acc[i][jj][2]); o.w = f2bf(acc[i][jj][3]);
        *(ushort4*)&Tbuf[(jl * 16 + c) * 136 + wr + i * 16 + q * 4] = o;
      }
    }
    __syncthreads();
#pragma unroll
    for (int it = 0; it < 4; ++it) {       // 1024 uint4 = 64 rows x 16
      int idx = it * 256 + tid;
      int row = idx >> 4, col8 = idx & 15;
      *(uint4*)&F[((size_t)(bh * kM + mc * 64 + row)) * (size_t)kL +
                  l0 + col8 * 8] = *(const uint4*)&Tbuf[row * 136 + col8 * 8];
    }
  }
}

// ---------------------------------------------------------------------------
// FUSED FAVOR-Q + attention read-out (r11: 46,080 B LDS, 3 blocks/CU).
// ---------------------------------------------------------------------------
__global__ __launch_bounds__(256) void fused_qf_attn(
    const unsigned short* __restrict__ U, const unsigned short* __restrict__ projb,
    const unsigned short* __restrict__ KVT, unsigned short* __restrict__ ATTN)
{
  __shared__ unsigned short SA[22016];   // 44,032 B union (see below)
  __shared__ float diagp[256];
  __shared__ float diag[128];
  __shared__ unsigned short ksumS[256];
  unsigned short* Us  = SA;              // [128][72] = 9216   (phase A)
  unsigned short* Ps2 = SA + 9216;       // [128][72] = 9216   (phase A, half)
  unsigned short* kvs = SA;              // [64][264] = 16896  (phase B)
  unsigned short* qs  = SA + 16896;      // [128][40] = 5120   (phase B)
  const int bh = blockIdx.x, b = bh >> 4, h = bh & 15;
  const int l0 = blockIdx.y * 128;
  const int tid = threadIdx.x, lane = tid & 63, w = tid >> 6;
  const int q = lane >> 4, c = lane & 15;
  const int wr = w * 32;

  // --- Phase A: dash + exp, proj staged in two 128-row halves ---
#pragma unroll
  for (int it = 0; it < 4; ++it) {
    int idx = it * 256 + tid;
    int row = idx >> 3, col8 = idx & 7;
    *(uint4*)&Us[row * 72 + col8 * 8] =
        *(const uint4*)&U[((size_t)(b * kL + l0 + row)) * kD + h * kDH + col8 * 8];
  }
#pragma unroll
  for (int it = 0; it < 4; ++it) {       // proj half 0: rows 0..127
    int idx = it * 256 + tid;
    int row = idx >> 3, col8 = idx & 7;
    *(uint4*)&Ps2[row * 72 + col8 * 8] =
        *(const uint4*)&projb[((size_t)(h * kM + row)) * kDH + col8 * 8];
  }
  __syncthreads();

  {
    int row = tid & 127, half = tid >> 7;
    const unsigned short* ur = &Us[row * 72 + half * 32];
    float s = 0.f;
#pragma unroll
    for (int d8 = 0; d8 < 4; ++d8) {
      uint4 raw = *(const uint4*)&ur[d8 * 8];
      const unsigned short* us = (const unsigned short*)&raw;
#pragma unroll
      for (int j = 0; j < 8; ++j) { float v = bf2f(us[j]); s = fmaf(v, v, s); }
    }
    diagp[half * 128 + row] = s;
  }

  f32x4 acc[2][16];
#pragma unroll
  for (int i = 0; i < 2; ++i)
#pragma unroll
    for (int j = 0; j < 16; ++j) acc[i][j] = (f32x4)0.f;

#pragma unroll
  for (int half = 0; half < 2; ++half) {
    if (half == 1) {
      __syncthreads();   // prior Ps2 reads done
#pragma unroll
      for (int it = 0; it < 4; ++it) {   // proj half 1: rows 128..255
        int idx = it * 256 + tid;
        int row = idx >> 3, col8 = idx & 7;
        *(uint4*)&Ps2[row * 72 + col8 * 8] =
            *(const uint4*)&projb[((size_t)(h * kM + 128 + row)) * kDH + col8 * 8];
      }
      __syncthreads();
    }
#pragma unroll
    for (int ks = 0; ks < 2; ++ks) {
      short8 av[2];
#pragma unroll
      for (int i = 0; i < 2; ++i)
        av[i] = *(const short8*)&Us[(wr + i * 16 + c) * 72 + ks * 32 + q * 8];
      short8 bv[8];
#pragma unroll
      for (int jl = 0; jl < 8; ++jl)
        bv[jl] = *(const short8*)&Ps2[(jl * 16 + c) * 72 + ks * 32 + q * 8];
#pragma unroll
      for (int jl = 0; jl < 8; ++jl)
#pragma unroll
        for (int i = 0; i < 2; ++i)
          acc[i][half * 8 + jl] = __builtin_amdgcn_mfma_f32_16x16x32_bf16(
              av[i], bv[jl], acc[i][half * 8 + jl], 0, 0, 0);
    }
  }

  __syncthreads();   // all Us/Ps2 reads complete; alias region reusable
  if (tid < 128) diag[tid] = 0.5f * (diagp[tid] + diagp[128 + tid]);
  // stage kvs: 64 rows x 256 cols = 2048 uint4, 8 per thread
#pragma unroll
  for (int it = 0; it < 8; ++it) {
    int idx = it * 256 + tid;
    int row = idx >> 5, col8 = (idx & 31) * 8;
    *(uint4*)&kvs[row * 264 + col8] =
        *(const uint4*)&KVT[(size_t)bh * (80 * kM) + row * kM + col8];
  }
  // stage ksum row (KVT row 64): 32 uint4
  if (tid < 32)
    *(uint4*)&ksumS[tid * 8] =
        *(const uint4*)&KVT[(size_t)bh * (80 * kM) + 64 * kM + tid * 8];
  __syncthreads();   // diag + kvs + ksum ready

  // exp epilogue in registers: acc <- exp(dash - diag - rowmax) * M^-0.5
#pragma unroll
  for (int i = 0; i < 2; ++i)
#pragma unroll
    for (int r = 0; r < 4; ++r) {
      const int lrow = wr + i * 16 + q * 4 + r;
      float mx = -3.4e38f;
#pragma unroll
      for (int j = 0; j < 16; ++j) mx = fmaxf(mx, acc[i][j][r]);
      mx = fmaxf(mx, __shfl_xor(mx, 1, 64));
      mx = fmaxf(mx, __shfl_xor(mx, 2, 64));
      mx = fmaxf(mx, __shfl_xor(mx, 4, 64));
      mx = fmaxf(mx, __shfl_xor(mx, 8, 64));
      const float base = diag[lrow] + mx;
#pragma unroll
      for (int j = 0; j < 16; ++j)
        acc[i][j][r] = __expf(acc[i][j][r] - base) * kInvSqrtM;
    }

  // denominator via VALU + shfl: den[row] = sum_m qf[row][m] * ksum[m]
  float z_[2][4];
#pragma unroll
  for (int i = 0; i < 2; ++i)
#pragma unroll
    for (int r = 0; r < 4; ++r) {
      float d = 0.f;
#pragma unroll
      for (int j = 0; j < 16; ++j)
        d = fmaf(acc[i][j][r], bf2f(ksumS[j * 16 + c]), d);
      d += __shfl_xor(d, 1, 64);
      d += __shfl_xor(d, 2, 64);
      d += __shfl_xor(d, 4, 64);
      d += __shfl_xor(d, 8, 64);
      z_[i][r] = 1.f / (d + kEps);
    }

  // --- Phase B: attn MFMA over 8 m-chunks of 32, 4 real n-tiles ---
  f32x4 acc2[2][4];
#pragma unroll
  for (int i = 0; i < 2; ++i)
#pragma unroll
    for (int j = 0; j < 4; ++j) acc2[i][j] = (f32x4)0.f;

#pragma unroll
  for (int kk = 0; kk < 8; ++kk) {
#pragma unroll
    for (int i = 0; i < 2; ++i)
#pragma unroll
      for (int jj2 = 0; jj2 < 2; ++jj2) {
        const int jj = kk * 2 + jj2;
#pragma unroll
        for (int r = 0; r < 4; ++r)
          qs[(wr + i * 16 + q * 4 + r) * 40 + jj2 * 16 + c] =
              f2bf(acc[i][jj][r]);
      }
    __syncthreads();
    short8 bv2[4];
#pragma unroll
    for (int j = 0; j < 4; ++j)
      bv2[j] = *(const short8*)&kvs[(j * 16 + c) * 264 + kk * 32 + q * 8];
#pragma unroll
    for (int i = 0; i < 2; ++i) {
      short8 av2 = *(const short8*)&qs[(w * 32 + i * 16 + c) * 40 + q * 8];
#pragma unroll
      for (int j = 0; j < 4; ++j)
        acc2[i][j] = __builtin_amdgcn_mfma_f32_16x16x32_bf16(
            av2, bv2[j], acc2[i][j], 0, 0, 0);
    }
    __syncthreads();   // qs consumed; next chunk may overwrite
  }

  // epilogue: scale by 1/den, write ATTN
#pragma unroll
  for (int i = 0; i < 2; ++i)
#pragma unroll
    for (int r = 0; r < 4; ++r) {
      const int row = l0 + w * 32 + i * 16 + q * 4 + r;
      const size_t base = ((size_t)(b * kL + row)) * kD + h * kDH;
#pragma unroll
      for (int j = 0; j < 4; ++j)
        ATTN[base + j * 16 + c] = f2bf(acc2[i][j][r] * z_[i][r]);
    }
}

// ---------------------------------------------------------------------------
// kv via MFMA, r8-proven m97-style async staging: per (bh, mtile, split):
// C[128 m][64 d] = KFT tile @ VT tile^T over 512 l. ksum from A-fragments.
// ---------------------------------------------------------------------------
__global__ __launch_bounds__(256) void kv_mfma(
    const unsigned short* __restrict__ KFT, const unsigned short* __restrict__ VT,
    float* __restrict__ KVP, float* __restrict__ KSP)
{
  __shared__ unsigned short As[128 * 32];   // 8 KB
  __shared__ unsigned short Bs[64 * 32];    // 4 KB
  const int bh = blockIdx.x, mtile = blockIdx.y, split = blockIdx.z;
  const int tid = threadIdx.x, lane = tid & 63, w = tid >> 6;
  const int q = lane >> 4, c = lane & 15;
  const int l0 = split * 512;
  const unsigned short* Abase = KFT + ((size_t)(bh * kM + mtile * 128)) * kL + l0;
  const unsigned short* Bbase = VT + ((size_t)(bh * kDH)) * kL + l0;
  const int lrow = lane >> 2, lcol = (lane & 3) * 8;

  f32x4 acc[2][4];
#pragma unroll
  for (int i = 0; i < 2; ++i)
#pragma unroll
    for (int j = 0; j < 4; ++j) acc[i][j] = (f32x4)0.f;
  float ksr[2] = {0.f, 0.f};

  for (int k0 = 0; k0 < 512; k0 += 32) {
#pragma unroll
    for (int i = 0; i < 2; ++i) {
      const int r0 = w * 32 + i * 16;
      gload_lds16(&Abase[(size_t)(r0 + lrow) * kL + k0 + lcol], &As[r0 * 32]);
    }
    gload_lds16(&Bbase[(size_t)(w * 16 + lrow) * kL + k0 + lcol], &Bs[w * 16 * 32]);
    __syncthreads();
    short8 av[2], bv[4];
#pragma unroll
    for (int i = 0; i < 2; ++i) {
      av[i] = *(const short8*)&As[(w * 32 + i * 16 + c) * 32 + q * 8];
#pragma unroll
      for (int e = 0; e < 8; ++e) ksr[i] += bf2f((unsigned short)av[i][e]);
    }
#pragma unroll
    for (int j = 0; j < 4; ++j)
      bv[j] = *(const short8*)&Bs[(j * 16 + c) * 32 + q * 8];
#pragma unroll
    for (int i = 0; i < 2; ++i)
#pragma unroll
      for (int j = 0; j < 4; ++j)
        acc[i][j] = __builtin_amdgcn_mfma_f32_16x16x32_bf16(
            av[i], bv[j], acc[i][j], 0, 0, 0);
    __syncthreads();
  }

  const int blk = (bh * 2 + mtile) * 8 + split;
  float* op = KVP + (size_t)blk * (128 * 64);
#pragma unroll
  for (int i = 0; i < 2; ++i)
#pragma unroll
    for (int j = 0; j < 4; ++j)
#pragma unroll
      for (int r = 0; r < 4; ++r)
        op[(w * 32 + i * 16 + q * 4 + r) * 64 + j * 16 + c] = acc[i][j][r];

#pragma unroll
  for (int i = 0; i < 2; ++i) {
    float s = ksr[i];
    s += __shfl_xor(s, 16, 64);
    s += __shfl_xor(s, 32, 64);
    if (q == 0) KSP[blk * 128 + w * 32 + i * 16 + c] = s;
  }
}

// Reduce 8 splits -> KVT' bf16 [bh][80][256]: rows 0..63 = kv^T[d][m],
// row 64 = ksum[m], rows 65..79 = 0 (pad rows kept for layout compat).
__global__ __launch_bounds__(256) void kv_reduce_kernel(
    const float* __restrict__ KVP, const float* __restrict__ KSP,
    unsigned short* __restrict__ KVT)
{
  const int blk = blockIdx.x;            // 32*80
  const int bh = blk / 80, n = blk - bh * 80;
  const int t = threadIdx.x;             // m
  const int mt = t >> 7, ml = t & 127;
  float s = 0.f;
  if (n < 64) {
#pragma unroll
    for (int sp = 0; sp < 8; ++sp)
      s += KVP[((size_t)((bh * 2 + mt) * 8 + sp)) * (128 * 64) + ml * 64 + n];
  } else if (n == 64) {
#pragma unroll
    for (int sp = 0; sp < 8; ++sp)
      s += KSP[((bh * 2 + mt) * 8 + sp) * 128 + ml];
  }
  KVT[(size_t)bh * (80 * kM) + n * kM + t] = f2bf(s);
}

// ---------------------------------------------------------------------------
// GELU (exact) + LayerNorm + 2x nearest-neighbor duplicate write.
// Reads Y as bf16 (written by gemm_wo) — halves the Y round trip.
// ---------------------------------------------------------------------------
__global__ __launch_bounds__(256) void gelu_ln_kernel(
    const unsigned short* __restrict__ Yb, const float* __restrict__ lng,
    const float* __restrict__ lnb, float* __restrict__ OUT)
{
  __shared__ float r1[4], r2[4];
  const int n = blockIdx.x;
  const int tid = threadIdx.x, lane = tid & 63, w = tid >> 6;

  ushort4 yv = ((const ushort4*)(Yb + (size_t)n * kD))[tid];
  float y0 = bf2f(yv.x), y1 = bf2f(yv.y), y2 = bf2f(yv.z), y3 = bf2f(yv.w);
  float g0 = 0.5f * y0 * (1.f + erff(y0 * 0.70710678118654752f));
  float g1 = 0.5f * y1 * (1.f + erff(y1 * 0.70710678118654752f));
  float g2 = 0.5f * y2 * (1.f + erff(y2 * 0.70710678118654752f));
  float g3 = 0.5f * y3 * (1.f + erff(y3 * 0.70710678118654752f));

  float s  = (g0 + g1) + (g2 + g3);
  float ss = (g0 * g0 + g1 * g1) + (g2 * g2 + g3 * g3);
#pragma unroll
  for (int off = 32; off; off >>= 1) {
    s  += __shfl_xor(s, off, 64);
    ss += __shfl_xor(ss, off, 64);
  }
  if (lane == 0) { r1[w] = s; r2[w] = ss; }
  __syncthreads();
  s  = (r1[0] + r1[1]) + (r1[2] + r1[3]);
  ss = (r2[0] + r2[1]) + (r2[2] + r2[3]);
  float mu  = s * (1.f / (float)kD);
  float var = ss * (1.f / (float)kD) - mu * mu;
  float inv = rsqrtf(var + kLnEps);

  float4 gg = ((const float4*)lng)[tid];
  float4 bb = ((const float4*)lnb)[tid];
  float4 o;
  o.x = (g0 - mu) * inv * gg.x + bb.x;
  o.y = (g1 - mu) * inv * gg.y + bb.y;
  o.z = (g2 - mu) * inv * gg.z + bb.z;
  o.w = (g3 - mu) * inv * gg.w + bb.w;

  const int b = n >> 12, l = n & 4095;
  const int cc = tid * 4;
  size_t base = ((size_t)(b * 8192 + 2 * l)) * kD + cc;
  *(float4*)(OUT + base)      = o;
  *(float4*)(OUT + base + kD) = o;
}

// ---------------------------------------------------------------------------
extern "C" void kernel_launch(void* const* d_in, const int* in_sizes, int n_in,
                              void* d_out, int out_size, void* d_ws, size_t ws_size,
                              hipStream_t stream)
{
  (void)in_sizes; (void)n_in; (void)out_size; (void)ws_size;
  const float* x    = (const float*)d_in[0];
  const float* Wq   = (const float*)d_in[1];
  const float* Wk   = (const float*)d_in[2];
  const float* Wv   = (const float*)d_in[3];
  const float* Wo   = (const float*)d_in[4];
  const float* proj = (const float*)d_in[5];
  const float* lng  = (const float*)d_in[6];
  const float* lnb  = (const float*)d_in[7];
  float* out = (float*)d_out;

  // Workspace layout (MB offsets):
  //  0   xb    bf16 [8192,1024]
  //  16  WqkvT bf16 [3072,1024] (Wq/Wk/Wv transposed, stacked)
  //  22  WoT   bf16 [1024,1024] transposed
  //  24  Qb    bf16 [8192,1024] (live until fused_qf_attn)
  //  40  Kb    bf16 (consumed by favor_k; reused as ATTN bf16)
  //  56  VT    bf16 [32 bh][64 d][4096 l]
  //  72  KVP   f32 [512][128*64] 16 MB (dead after kv_reduce; Yb reuses)
  //  136 KFT   bf16 [32 bh][256 m][4096 l]
  //  200 KSP   f32 [512][128]
  //  201 KVT   bf16 [32,80,256]
  //  203 projb bf16 [16,256,64]
  char* ws = (char*)d_ws;
  const size_t MB = 1024 * 1024;
  unsigned short* xb    = (unsigned short*)(ws);
  unsigned short* WqkvT = (unsigned short*)(ws + 16 * MB);
  unsigned short* WoT   = (unsigned short*)(ws + 22 * MB);
  unsigned short* Qb    = (unsigned short*)(ws + 24 * MB);
  unsigned short* Kb    = (unsigned short*)(ws + 40 * MB);
  unsigned short* VT    = (unsigned short*)(ws + 56 * MB);
  float* KVP            = (float*)(ws + 72 * MB);
  unsigned short* KFT   = (unsigned short*)(ws + 136 * MB);
  float* KSP            = (float*)(ws + 200 * MB);
  unsigned short* KVT   = (unsigned short*)(ws + 201 * MB);
  unsigned short* projb = (unsigned short*)(ws + 203 * MB);
  unsigned short* ATTN  = Kb;                       // after favor_k consumed Kb
  unsigned short* Yb    = (unsigned short*)(ws + 72 * MB);  // after KVP dead
  unsigned short* WvT   = WqkvT + (size_t)2 * kD * kD;

  // 1) casts + weight transposes (one launch)
  cast_bf16_kernel<<<(kN * kD) / 1024, 256, 0, stream>>>(x, xb);
  cast_bf16_kernel<<<(kH * kM * kDH) / 1024, 256, 0, stream>>>(proj, projb);
  transpose_cast4_kernel<<<dim3(32, 32, 4), 256, 0, stream>>>(
      Wq, Wk, Wv, Wo, WqkvT, WoT);

  // 2) projections: merged Q+K; V^T direct via swapped-operand GEMM
  gemm_qk_mfma<<<dim3(16, 64), 256, 0, stream>>>(xb, WqkvT, Qb, Kb);
  gemm_vt_mfma<<<dim3(8, 64), 256, 0, stream>>>(WvT, xb, VT);

  // 3) FAVOR-K (stored transposed), then kv / ksum, reduce to KVT'
  favor_k_mfma<<<dim3(32, 32), 256, 0, stream>>>(Kb, projb, KFT);
  kv_mfma<<<dim3(32, 2, 8), 256, 0, stream>>>(KFT, VT, KVP, KSP);
  kv_reduce_kernel<<<32 * 80, 256, 0, stream>>>(KVP, KSP, KVT);

  // 4) fused FAVOR-Q + attention read-out -> bf16 ATTN (QF eliminated)
  fused_qf_attn<<<dim3(32, 32), 256, 0, stream>>>(Qb, projb, KVT, ATTN);

  // 5) output projection (bf16 out)
  gemm_wo_mfma<<<dim3(8, 64), 256, 0, stream>>>(ATTN, WoT, Yb);

  // 6) GELU + LayerNorm + 2x duplicate write
  gelu_ln_kernel<<<kN, 256, 0, stream>>>(Yb, lng, lnb, out);
}

// Round 13
// 324.738 us; speedup vs baseline: 1.0509x; 1.0134x over previous
//
#include <hip/hip_runtime.h>

// Problem constants (fixed by the reference).
static constexpr int kB  = 2;
static constexpr int kL  = 4096;   // source sequence length
static constexpr int kD  = 1024;
static constexpr int kH  = 16;
static constexpr int kDH = 64;
static constexpr int kM  = 256;
static constexpr int kN  = kB * kL;              // 8192 deduplicated rows
static constexpr float kScale    = 0.35355339059327373f;  // DH^-0.25
static constexpr float kInvSqrtM = 0.0625f;               // M^-0.5
static constexpr float kEps   = 1e-6f;
static constexpr float kLnEps = 1e-5f;

typedef __attribute__((ext_vector_type(8))) short short8;   // 8 bf16 (4 VGPRs)
typedef __attribute__((ext_vector_type(4))) float f32x4;

__device__ __forceinline__ float bf2f(unsigned short h) {
  union { unsigned int u; float f; } c;
  c.u = ((unsigned int)h) << 16;
  return c.f;
}
__device__ __forceinline__ unsigned short f2bf(float f) {
  union { float f; unsigned int u; } c;
  c.f = f;
  unsigned int u = c.u;
  u += 0x7fffu + ((u >> 16) & 1u);   // round-to-nearest-even
  return (unsigned short)(u >> 16);
}

// async global->LDS, 16 B per lane; LDS dest = wave-uniform base + lane*16.
__device__ __forceinline__ void gload_lds16(const unsigned short* g,
                                            unsigned short* l) {
  __builtin_amdgcn_global_load_lds(
      (const __attribute__((address_space(1))) unsigned int*)g,
      (__attribute__((address_space(3))) unsigned int*)l, 16, 0, 0);
}

// Bijective XCD-chunked block remap (nwg must be a multiple of 8).
__device__ __forceinline__ void xcd_swizzle(int& bx, int& by) {
  const int nwg = gridDim.x * gridDim.y;
  const int bid = blockIdx.x + gridDim.x * blockIdx.y;
  const int cpx = nwg >> 3;
  const int sb  = (bid & 7) * cpx + (bid >> 3);
  bx = sb % gridDim.x;
  by = sb / gridDim.x;
}

// ---------------------------------------------------------------------------
// casts
// ---------------------------------------------------------------------------
__global__ __launch_bounds__(256) void cast_bf16_kernel(
    const float* __restrict__ in, unsigned short* __restrict__ out)
{
  const int i = blockIdx.x * 256 + threadIdx.x;
  float4 v = ((const float4*)in)[i];
  ushort4 o;
  o.x = f2bf(v.x); o.y = f2bf(v.y); o.z = f2bf(v.z); o.w = f2bf(v.w);
  ((ushort4*)out)[i] = o;
}

// All four weight transposes in one launch. z in {0,1,2}: Wq/Wk/Wv into
// WqkvT[3072][1024] at row offset z*1024; z==3: Wo into WoT.
__global__ __launch_bounds__(256) void transpose_cast4_kernel(
    const float* __restrict__ W0, const float* __restrict__ W1,
    const float* __restrict__ W2, const float* __restrict__ W3,
    unsigned short* __restrict__ WqkvT, unsigned short* __restrict__ WoT)
{
  __shared__ float tile[32][33];
  const int z = blockIdx.z;
  const float* W = (z == 0) ? W0 : (z == 1) ? W1 : (z == 2) ? W2 : W3;
  unsigned short* WT = (z < 3) ? (WqkvT + (size_t)z * kD * kD) : WoT;
  const int n0 = blockIdx.x * 32, k0 = blockIdx.y * 32;
  const int t = threadIdx.x, kk = t >> 5, nn = t & 31;
#pragma unroll
  for (int i = 0; i < 4; ++i)
    tile[kk + i * 8][nn] = W[(size_t)(k0 + kk + i * 8) * kD + n0 + nn];
  __syncthreads();
#pragma unroll
  for (int i = 0; i < 4; ++i)
    WT[(size_t)(n0 + kk + i * 8) * kD + k0 + nn] = f2bf(tile[nn][kk + i * 8]);
}

// ---------------------------------------------------------------------------
// BK=64 K-loop GEMM body (r12-proven: bank-conflict-free). 16 K-steps.
// Global SOURCE pre-swizzled per-lane (chunk ^= row&7), LDS dest linear,
// fragment reads apply the same XOR. LDS[row][cs] = global[row][cs^(row&7)].
// ---------------------------------------------------------------------------
#define GEMM_BK64_BODY(Aptr, Bptr, arow0, bcol0)                              \
  const int lrow = lane >> 3;                                                 \
  const int lcol = ((lane & 7) ^ lrow) * 8; /* swizzled global chunk */       \
  f32x4 acc[4][4];                                                            \
  _Pragma("unroll")                                                           \
  for (int i = 0; i < 4; ++i)                                                 \
    _Pragma("unroll")                                                         \
    for (int j = 0; j < 4; ++j) acc[i][j] = (f32x4)0.f;                       \
  for (int k0 = 0; k0 < kD; k0 += 64) {                                       \
    _Pragma("unroll")                                                         \
    for (int i = 0; i < 4; ++i) {                                             \
      const int r0 = w * 32 + i * 8;                                          \
      gload_lds16(&Aptr[(size_t)(arow0 + r0 + lrow) * kD + k0 + lcol],        \
                  &As[r0 * 64]);                                              \
      gload_lds16(&Bptr[(size_t)(bcol0 + r0 + lrow) * kD + k0 + lcol],        \
                  &Bs[r0 * 64]);                                              \
    }                                                                         \
    __syncthreads();                                                          \
    _Pragma("unroll")                                                         \
    for (int ks = 0; ks < 2; ++ks) {                                          \
      short8 av[4], bv[4];                                                    \
      const int ch = ks * 4 + q;                                              \
      _Pragma("unroll")                                                       \
      for (int i = 0; i < 4; ++i)                                             \
        av[i] = *(const short8*)&As[(wr + i * 16 + c) * 64 +                  \
                                    ((ch ^ (c & 7)) * 8)];                    \
      _Pragma("unroll")                                                       \
      for (int j = 0; j < 4; ++j)                                             \
        bv[j] = *(const short8*)&Bs[(wc + j * 16 + c) * 64 +                  \
                                    ((ch ^ (c & 7)) * 8)];                    \
      _Pragma("unroll")                                                       \
      for (int i = 0; i < 4; ++i)                                             \
        _Pragma("unroll")                                                     \
        for (int j = 0; j < 4; ++j)                                           \
          acc[i][j] = __builtin_amdgcn_mfma_f32_16x16x32_bf16(                \
              av[i], bv[j], acc[i][j], 0, 0, 0);                              \
    }                                                                         \
    __syncthreads();                                                          \
  }

// ---------------------------------------------------------------------------
// Merged Q+K+V projection GEMM (BK=64 swizzled, XCD-swizzled). Grid 24x64.
// bx<16: QK path — A=xb rows (by), BT=WqkvT cols (bx), plain bf16*kScale
//        store to Qb/Kb.
// bx>=16: VT path — swapped operands: A=WvT rows ((bx-16)), BT=xb "cols"
//        (by); output is VT row-major natively, plain bf16 store.
// Both epilogues are store-only (no Tbuf; the r5 merge pathology is absent):
// identical 32.8 KB LDS, wave-uniform branch.
// ---------------------------------------------------------------------------
__global__ __launch_bounds__(256) void gemm_qkv_mfma(
    const unsigned short* __restrict__ xb, const unsigned short* __restrict__ WqkvT,
    unsigned short* __restrict__ Qb, unsigned short* __restrict__ Kb,
    unsigned short* __restrict__ VT)
{
  __shared__ unsigned short As[128 * 64];   // 16 KB
  __shared__ unsigned short Bs[128 * 64];   // 16 KB
  const int tid = threadIdx.x, lane = tid & 63, w = tid >> 6;
  const int q = lane >> 4, c = lane & 15;
  const int wr = (w >> 1) * 64, wc = (w & 1) * 64;
  int bx, by; xcd_swizzle(bx, by);
  const bool isv = (bx >= 16);
  const unsigned short* WvT = WqkvT + (size_t)2 * kD * kD;
  const unsigned short* Ap = isv ? WvT : xb;
  const unsigned short* Bp = isv ? xb : WqkvT;
  const int arow0 = isv ? (bx - 16) * 128 : by * 128;
  const int bcol0 = isv ? by * 128 : bx * 128;

  GEMM_BK64_BODY(Ap, Bp, arow0, bcol0)

  if (!isv) {
    unsigned short* O = (bcol0 < 1024) ? Qb : Kb;
    const int cl0 = bcol0 & 1023;
#pragma unroll
    for (int i = 0; i < 4; ++i)
#pragma unroll
      for (int j = 0; j < 4; ++j)
#pragma unroll
        for (int r = 0; r < 4; ++r) {
          const int row = arow0 + wr + i * 16 + q * 4 + r;
          const int col = cl0 + wc + j * 16 + c;
          O[(size_t)row * kD + col] = f2bf(kScale * acc[i][j][r]);
        }
  } else {
    // row = output V-channel (h*64+d), col = b*4096 + l
#pragma unroll
    for (int i = 0; i < 4; ++i)
#pragma unroll
      for (int j = 0; j < 4; ++j)
#pragma unroll
        for (int r = 0; r < 4; ++r) {
          const int row = arow0 + wr + i * 16 + q * 4 + r;
          const int col = bcol0 + wc + j * 16 + c;
          const int bq = col >> 12, l = col & 4095;
          const int h = row >> 6, d = row & 63;
          VT[((size_t)((bq * 16 + h) * 64 + d)) * (size_t)kL + l] =
              f2bf(acc[i][j][r]);
        }
  }
}

// ---------------------------------------------------------------------------
// Wo projection GEMM (BK=64 swizzled), bf16 row-major out (Yb).
// ---------------------------------------------------------------------------
__global__ __launch_bounds__(256) void gemm_wo_mfma(
    const unsigned short* __restrict__ A, const unsigned short* __restrict__ BT,
    unsigned short* __restrict__ Yb)
{
  __shared__ unsigned short As[128 * 64];
  __shared__ unsigned short Bs[128 * 64];
  const int tid = threadIdx.x, lane = tid & 63, w = tid >> 6;
  const int q = lane >> 4, c = lane & 15;
  const int wr = (w >> 1) * 64, wc = (w & 1) * 64;
  int bx, by; xcd_swizzle(bx, by);
  const int row0 = by * 128, col0 = bx * 128;

  GEMM_BK64_BODY(A, BT, row0, col0)

#pragma unroll
  for (int i = 0; i < 4; ++i)
#pragma unroll
    for (int j = 0; j < 4; ++j)
#pragma unroll
      for (int r = 0; r < 4; ++r) {
        const int row = row0 + wr + i * 16 + q * 4 + r;
        const int col = col0 + wc + j * 16 + c;
        Yb[(size_t)row * kD + col] = f2bf(acc[i][j][r]);
      }
}

// ---------------------------------------------------------------------------
// FAVOR-K via MFMA (r4/r8-proven TRANS=1 path): proj staged in LDS, Tbuf
// aliased onto Us. Stores KFT [bh][m][l] via 64-row LDS chunks. 56,832 B.
// ---------------------------------------------------------------------------
__global__ __launch_bounds__(256) void favor_k_mfma(
    const unsigned short* __restrict__ U, const unsigned short* __restrict__ projb,
    unsigned short* __restrict__ F)
{
  __shared__ unsigned short Us[128 * 72];    // 18.4 KB; reused as Tbuf later
  __shared__ unsigned short Ps[256 * 72];    // 36.9 KB, proj head, pad 72
  __shared__ float diagp[256];
  __shared__ float diag[128];
  unsigned short* Tbuf = Us;                 // alias: 64*136 = 8704 <= 9216
  const int bh = blockIdx.x, b = bh >> 4, h = bh & 15;
  const int l0 = blockIdx.y * 128;
  const int tid = threadIdx.x, lane = tid & 63, w = tid >> 6;
  const int q = lane >> 4, c = lane & 15;
  const int wr = w * 32;

#pragma unroll
  for (int it = 0; it < 4; ++it) {
    int idx = it * 256 + tid;
    int row = idx >> 3, col8 = idx & 7;
    *(uint4*)&Us[row * 72 + col8 * 8] =
        *(const uint4*)&U[((size_t)(b * kL + l0 + row)) * kD + h * kDH + col8 * 8];
  }
#pragma unroll
  for (int it = 0; it < 8; ++it) {
    int idx = it * 256 + tid;
    int row = idx >> 3, col8 = idx & 7;
    *(uint4*)&Ps[row * 72 + col8 * 8] =
        *(const uint4*)&projb[((size_t)(h * kM + row)) * kDH + col8 * 8];
  }
  __syncthreads();

  {
    int row = tid & 127, half = tid >> 7;
    const unsigned short* ur = &Us[row * 72 + half * 32];
    float s = 0.f;
#pragma unroll
    for (int d8 = 0; d8 < 4; ++d8) {
      uint4 raw = *(const uint4*)&ur[d8 * 8];
      const unsigned short* us = (const unsigned short*)&raw;
#pragma unroll
      for (int j = 0; j < 8; ++j) { float v = bf2f(us[j]); s = fmaf(v, v, s); }
    }
    diagp[half * 128 + row] = s;
  }

  f32x4 acc[2][16];
#pragma unroll
  for (int i = 0; i < 2; ++i)
#pragma unroll
    for (int j = 0; j < 16; ++j) acc[i][j] = (f32x4)0.f;

#pragma unroll
  for (int ks = 0; ks < 2; ++ks) {
    short8 av[2];
#pragma unroll
    for (int i = 0; i < 2; ++i)
      av[i] = *(const short8*)&Us[(wr + i * 16 + c) * 72 + ks * 32 + q * 8];
#pragma unroll
    for (int jb = 0; jb < 2; ++jb) {
      short8 bv[8];
#pragma unroll
      for (int jl = 0; jl < 8; ++jl)
        bv[jl] = *(const short8*)&Ps[((jb * 8 + jl) * 16 + c) * 72 + ks * 32 + q * 8];
#pragma unroll
      for (int jl = 0; jl < 8; ++jl)
#pragma unroll
        for (int i = 0; i < 2; ++i)
          acc[i][jb * 8 + jl] = __builtin_amdgcn_mfma_f32_16x16x32_bf16(
              av[i], bv[jl], acc[i][jb * 8 + jl], 0, 0, 0);
    }
  }

  __syncthreads();   // all Us reads complete (required: Tbuf aliases Us)
  if (tid < 128) diag[tid] = 0.5f * (diagp[tid] + diagp[128 + tid]);
  __syncthreads();

#pragma unroll
  for (int i = 0; i < 2; ++i)
#pragma unroll
    for (int r = 0; r < 4; ++r) {
      const int lrow = wr + i * 16 + q * 4 + r;
      float mx = -3.4e38f;
#pragma unroll
      for (int j = 0; j < 16; ++j) mx = fmaxf(mx, acc[i][j][r]);
      mx = fmaxf(mx, __shfl_xor(mx, 1, 64));
      mx = fmaxf(mx, __shfl_xor(mx, 2, 64));
      mx = fmaxf(mx, __shfl_xor(mx, 4, 64));
      mx = fmaxf(mx, __shfl_xor(mx, 8, 64));
      const float base = diag[lrow] + mx;
#pragma unroll
      for (int j = 0; j < 16; ++j)
        acc[i][j][r] = __expf(acc[i][j][r] - base) * kInvSqrtM;
    }

  // LDS-transpose 64-m chunks, store KFT[bh*256 + m][l0..l0+128).
#pragma unroll
  for (int mc = 0; mc < 4; ++mc) {
    __syncthreads();
#pragma unroll
    for (int jl = 0; jl < 4; ++jl) {
      const int jj = mc * 4 + jl;
#pragma unroll
      for (int i = 0; i < 2; ++i) {
        ushort4 o;
        o.x = f2bf(acc[i][jj][0]); o.y = f2bf(acc[i][jj][1]);
        o.z = f2bf(acc[i][jj][2]); o.w = f2bf(acc[i][jj][3]);
        *(ushort4*)&Tbuf[(jl * 16 + c) * 136 + wr + i * 16 + q * 4] = o;
      }
    }
    __syncthreads();
#pragma unroll
    for (int it = 0; it < 4; ++it) {       // 1024 uint4 = 64 rows x 16
      int idx = it * 256 + tid;
      int row = idx >> 4, col8 = idx & 15;
      *(uint4*)&F[((size_t)(bh * kM + mc * 64 + row)) * (size_t)kL +
                  l0 + col8 * 8] = *(const uint4*)&Tbuf[row * 136 + col8 * 8];
    }
  }
}

// ---------------------------------------------------------------------------
// FUSED FAVOR-Q + attention read-out (r11: 46,080 B LDS, 3 blocks/CU).
// ---------------------------------------------------------------------------
__global__ __launch_bounds__(256) void fused_qf_attn(
    const unsigned short* __restrict__ U, const unsigned short* __restrict__ projb,
    const unsigned short* __restrict__ KVT, unsigned short* __restrict__ ATTN)
{
  __shared__ unsigned short SA[22016];   // 44,032 B union (see below)
  __shared__ float diagp[256];
  __shared__ float diag[128];
  __shared__ unsigned short ksumS[256];
  unsigned short* Us  = SA;              // [128][72] = 9216   (phase A)
  unsigned short* Ps2 = SA + 9216;       // [128][72] = 9216   (phase A, half)
  unsigned short* kvs = SA;              // [64][264] = 16896  (phase B)
  unsigned short* qs  = SA + 16896;      // [128][40] = 5120   (phase B)
  const int bh = blockIdx.x, b = bh >> 4, h = bh & 15;
  const int l0 = blockIdx.y * 128;
  const int tid = threadIdx.x, lane = tid & 63, w = tid >> 6;
  const int q = lane >> 4, c = lane & 15;
  const int wr = w * 32;

  // --- Phase A: dash + exp, proj staged in two 128-row halves ---
#pragma unroll
  for (int it = 0; it < 4; ++it) {
    int idx = it * 256 + tid;
    int row = idx >> 3, col8 = idx & 7;
    *(uint4*)&Us[row * 72 + col8 * 8] =
        *(const uint4*)&U[((size_t)(b * kL + l0 + row)) * kD + h * kDH + col8 * 8];
  }
#pragma unroll
  for (int it = 0; it < 4; ++it) {       // proj half 0: rows 0..127
    int idx = it * 256 + tid;
    int row = idx >> 3, col8 = idx & 7;
    *(uint4*)&Ps2[row * 72 + col8 * 8] =
        *(const uint4*)&projb[((size_t)(h * kM + row)) * kDH + col8 * 8];
  }
  __syncthreads();

  {
    int row = tid & 127, half = tid >> 7;
    const unsigned short* ur = &Us[row * 72 + half * 32];
    float s = 0.f;
#pragma unroll
    for (int d8 = 0; d8 < 4; ++d8) {
      uint4 raw = *(const uint4*)&ur[d8 * 8];
      const unsigned short* us = (const unsigned short*)&raw;
#pragma unroll
      for (int j = 0; j < 8; ++j) { float v = bf2f(us[j]); s = fmaf(v, v, s); }
    }
    diagp[half * 128 + row] = s;
  }

  f32x4 acc[2][16];
#pragma unroll
  for (int i = 0; i < 2; ++i)
#pragma unroll
    for (int j = 0; j < 16; ++j) acc[i][j] = (f32x4)0.f;

#pragma unroll
  for (int half = 0; half < 2; ++half) {
    if (half == 1) {
      __syncthreads();   // prior Ps2 reads done
#pragma unroll
      for (int it = 0; it < 4; ++it) {   // proj half 1: rows 128..255
        int idx = it * 256 + tid;
        int row = idx >> 3, col8 = idx & 7;
        *(uint4*)&Ps2[row * 72 + col8 * 8] =
            *(const uint4*)&projb[((size_t)(h * kM + 128 + row)) * kDH + col8 * 8];
      }
      __syncthreads();
    }
#pragma unroll
    for (int ks = 0; ks < 2; ++ks) {
      short8 av[2];
#pragma unroll
      for (int i = 0; i < 2; ++i)
        av[i] = *(const short8*)&Us[(wr + i * 16 + c) * 72 + ks * 32 + q * 8];
      short8 bv[8];
#pragma unroll
      for (int jl = 0; jl < 8; ++jl)
        bv[jl] = *(const short8*)&Ps2[(jl * 16 + c) * 72 + ks * 32 + q * 8];
#pragma unroll
      for (int jl = 0; jl < 8; ++jl)
#pragma unroll
        for (int i = 0; i < 2; ++i)
          acc[i][half * 8 + jl] = __builtin_amdgcn_mfma_f32_16x16x32_bf16(
              av[i], bv[jl], acc[i][half * 8 + jl], 0, 0, 0);
    }
  }

  __syncthreads();   // all Us/Ps2 reads complete; alias region reusable
  if (tid < 128) diag[tid] = 0.5f * (diagp[tid] + diagp[128 + tid]);
  // stage kvs: 64 rows x 256 cols = 2048 uint4, 8 per thread
#pragma unroll
  for (int it = 0; it < 8; ++it) {
    int idx = it * 256 + tid;
    int row = idx >> 5, col8 = (idx & 31) * 8;
    *(uint4*)&kvs[row * 264 + col8] =
        *(const uint4*)&KVT[(size_t)bh * (80 * kM) + row * kM + col8];
  }
  // stage ksum row (KVT row 64): 32 uint4
  if (tid < 32)
    *(uint4*)&ksumS[tid * 8] =
        *(const uint4*)&KVT[(size_t)bh * (80 * kM) + 64 * kM + tid * 8];
  __syncthreads();   // diag + kvs + ksum ready

  // exp epilogue in registers: acc <- exp(dash - diag - rowmax) * M^-0.5
#pragma unroll
  for (int i = 0; i < 2; ++i)
#pragma unroll
    for (int r = 0; r < 4; ++r) {
      const int lrow = wr + i * 16 + q * 4 + r;
      float mx = -3.4e38f;
#pragma unroll
      for (int j = 0; j < 16; ++j) mx = fmaxf(mx, acc[i][j][r]);
      mx = fmaxf(mx, __shfl_xor(mx, 1, 64));
      mx = fmaxf(mx, __shfl_xor(mx, 2, 64));
      mx = fmaxf(mx, __shfl_xor(mx, 4, 64));
      mx = fmaxf(mx, __shfl_xor(mx, 8, 64));
      const float base = diag[lrow] + mx;
#pragma unroll
      for (int j = 0; j < 16; ++j)
        acc[i][j][r] = __expf(acc[i][j][r] - base) * kInvSqrtM;
    }

  // denominator via VALU + shfl: den[row] = sum_m qf[row][m] * ksum[m]
  float z_[2][4];
#pragma unroll
  for (int i = 0; i < 2; ++i)
#pragma unroll
    for (int r = 0; r < 4; ++r) {
      float d = 0.f;
#pragma unroll
      for (int j = 0; j < 16; ++j)
        d = fmaf(acc[i][j][r], bf2f(ksumS[j * 16 + c]), d);
      d += __shfl_xor(d, 1, 64);
      d += __shfl_xor(d, 2, 64);
      d += __shfl_xor(d, 4, 64);
      d += __shfl_xor(d, 8, 64);
      z_[i][r] = 1.f / (d + kEps);
    }

  // --- Phase B: attn MFMA over 8 m-chunks of 32, 4 real n-tiles ---
  f32x4 acc2[2][4];
#pragma unroll
  for (int i = 0; i < 2; ++i)
#pragma unroll
    for (int j = 0; j < 4; ++j) acc2[i][j] = (f32x4)0.f;

#pragma unroll
  for (int kk = 0; kk < 8; ++kk) {
#pragma unroll
    for (int i = 0; i < 2; ++i)
#pragma unroll
      for (int jj2 = 0; jj2 < 2; ++jj2) {
        const int jj = kk * 2 + jj2;
#pragma unroll
        for (int r = 0; r < 4; ++r)
          qs[(wr + i * 16 + q * 4 + r) * 40 + jj2 * 16 + c] =
              f2bf(acc[i][jj][r]);
      }
    __syncthreads();
    short8 bv2[4];
#pragma unroll
    for (int j = 0; j < 4; ++j)
      bv2[j] = *(const short8*)&kvs[(j * 16 + c) * 264 + kk * 32 + q * 8];
#pragma unroll
    for (int i = 0; i < 2; ++i) {
      short8 av2 = *(const short8*)&qs[(w * 32 + i * 16 + c) * 40 + q * 8];
#pragma unroll
      for (int j = 0; j < 4; ++j)
        acc2[i][j] = __builtin_amdgcn_mfma_f32_16x16x32_bf16(
            av2, bv2[j], acc2[i][j], 0, 0, 0);
    }
    __syncthreads();   // qs consumed; next chunk may overwrite
  }

  // epilogue: scale by 1/den, write ATTN
#pragma unroll
  for (int i = 0; i < 2; ++i)
#pragma unroll
    for (int r = 0; r < 4; ++r) {
      const int row = l0 + w * 32 + i * 16 + q * 4 + r;
      const size_t base = ((size_t)(b * kL + row)) * kD + h * kDH;
#pragma unroll
      for (int j = 0; j < 4; ++j)
        ATTN[base + j * 16 + c] = f2bf(acc2[i][j][r] * z_[i][r]);
    }
}

// ---------------------------------------------------------------------------
// kv via MFMA, BK=64 swizzled (r12 GEMM math transferred): per (bh, mtile,
// split): C[128 m][64 d] = KFT tile @ VT tile^T over 512 l, 8 K-steps.
// ksum[m] from A-fragments (both ks chunks per step cover all 64 cols).
// ---------------------------------------------------------------------------
__global__ __launch_bounds__(256) void kv_mfma(
    const unsigned short* __restrict__ KFT, const unsigned short* __restrict__ VT,
    float* __restrict__ KVP, float* __restrict__ KSP)
{
  __shared__ unsigned short As[128 * 64];   // 16 KB
  __shared__ unsigned short Bs[64 * 64];    // 8 KB
  const int bh = blockIdx.x, mtile = blockIdx.y, split = blockIdx.z;
  const int tid = threadIdx.x, lane = tid & 63, w = tid >> 6;
  const int q = lane >> 4, c = lane & 15;
  const int l0 = split * 512;
  const unsigned short* Abase = KFT + ((size_t)(bh * kM + mtile * 128)) * kL + l0;
  const unsigned short* Bbase = VT + ((size_t)(bh * kDH)) * kL + l0;
  const int lrow = lane >> 3;
  const int lcol = ((lane & 7) ^ lrow) * 8;   // swizzled global chunk

  f32x4 acc[2][4];
#pragma unroll
  for (int i = 0; i < 2; ++i)
#pragma unroll
    for (int j = 0; j < 4; ++j) acc[i][j] = (f32x4)0.f;
  float ksr[2] = {0.f, 0.f};

  for (int k0 = 0; k0 < 512; k0 += 64) {
#pragma unroll
    for (int i = 0; i < 4; ++i) {
      const int r0 = w * 32 + i * 8;
      gload_lds16(&Abase[(size_t)(r0 + lrow) * kL + k0 + lcol], &As[r0 * 64]);
    }
#pragma unroll
    for (int i = 0; i < 2; ++i) {
      const int r0 = w * 16 + i * 8;
      gload_lds16(&Bbase[(size_t)(r0 + lrow) * kL + k0 + lcol], &Bs[r0 * 64]);
    }
    __syncthreads();
#pragma unroll
    for (int ks = 0; ks < 2; ++ks) {
      short8 av[2], bv[4];
      const int ch = ks * 4 + q;
#pragma unroll
      for (int i = 0; i < 2; ++i) {
        av[i] = *(const short8*)&As[(w * 32 + i * 16 + c) * 64 +
                                    ((ch ^ (c & 7)) * 8)];
#pragma unroll
        for (int e = 0; e < 8; ++e) ksr[i] += bf2f((unsigned short)av[i][e]);
      }
#pragma unroll
      for (int j = 0; j < 4; ++j)
        bv[j] = *(const short8*)&Bs[(j * 16 + c) * 64 + ((ch ^ (c & 7)) * 8)];
#pragma unroll
      for (int i = 0; i < 2; ++i)
#pragma unroll
        for (int j = 0; j < 4; ++j)
          acc[i][j] = __builtin_amdgcn_mfma_f32_16x16x32_bf16(
              av[i], bv[j], acc[i][j], 0, 0, 0);
    }
    __syncthreads();
  }

  const int blk = (bh * 2 + mtile) * 8 + split;
  float* op = KVP + (size_t)blk * (128 * 64);
#pragma unroll
  for (int i = 0; i < 2; ++i)
#pragma unroll
    for (int j = 0; j < 4; ++j)
#pragma unroll
      for (int r = 0; r < 4; ++r)
        op[(w * 32 + i * 16 + q * 4 + r) * 64 + j * 16 + c] = acc[i][j][r];

#pragma unroll
  for (int i = 0; i < 2; ++i) {
    float s = ksr[i];
    s += __shfl_xor(s, 16, 64);
    s += __shfl_xor(s, 32, 64);
    if (q == 0) KSP[blk * 128 + w * 32 + i * 16 + c] = s;
  }
}

// Reduce 8 splits -> KVT' bf16 [bh][80][256]: rows 0..63 = kv^T[d][m],
// row 64 = ksum[m], rows 65..79 = 0 (pad rows kept for layout compat).
__global__ __launch_bounds__(256) void kv_reduce_kernel(
    const float* __restrict__ KVP, const float* __restrict__ KSP,
    unsigned short* __restrict__ KVT)
{
  const int blk = blockIdx.x;            // 32*80
  const int bh = blk / 80, n = blk - bh * 80;
  const int t = threadIdx.x;             // m
  const int mt = t >> 7, ml = t & 127;
  float s = 0.f;
  if (n < 64) {
#pragma unroll
    for (int sp = 0; sp < 8; ++sp)
      s += KVP[((size_t)((bh * 2 + mt) * 8 + sp)) * (128 * 64) + ml * 64 + n];
  } else if (n == 64) {
#pragma unroll
    for (int sp = 0; sp < 8; ++sp)
      s += KSP[((bh * 2 + mt) * 8 + sp) * 128 + ml];
  }
  KVT[(size_t)bh * (80 * kM) + n * kM + t] = f2bf(s);
}

// ---------------------------------------------------------------------------
// GELU (exact) + LayerNorm + 2x nearest-neighbor duplicate write.
// Reads Y as bf16 (written by gemm_wo) — halves the Y round trip.
// ---------------------------------------------------------------------------
__global__ __launch_bounds__(256) void gelu_ln_kernel(
    const unsigned short* __restrict__ Yb, const float* __restrict__ lng,
    const float* __restrict__ lnb, float* __restrict__ OUT)
{
  __shared__ float r1[4], r2[4];
  const int n = blockIdx.x;
  const int tid = threadIdx.x, lane = tid & 63, w = tid >> 6;

  ushort4 yv = ((const ushort4*)(Yb + (size_t)n * kD))[tid];
  float y0 = bf2f(yv.x), y1 = bf2f(yv.y), y2 = bf2f(yv.z), y3 = bf2f(yv.w);
  float g0 = 0.5f * y0 * (1.f + erff(y0 * 0.70710678118654752f));
  float g1 = 0.5f * y1 * (1.f + erff(y1 * 0.70710678118654752f));
  float g2 = 0.5f * y2 * (1.f + erff(y2 * 0.70710678118654752f));
  float g3 = 0.5f * y3 * (1.f + erff(y3 * 0.70710678118654752f));

  float s  = (g0 + g1) + (g2 + g3);
  float ss = (g0 * g0 + g1 * g1) + (g2 * g2 + g3 * g3);
#pragma unroll
  for (int off = 32; off; off >>= 1) {
    s  += __shfl_xor(s, off, 64);
    ss += __shfl_xor(ss, off, 64);
  }
  if (lane == 0) { r1[w] = s; r2[w] = ss; }
  __syncthreads();
  s  = (r1[0] + r1[1]) + (r1[2] + r1[3]);
  ss = (r2[0] + r2[1]) + (r2[2] + r2[3]);
  float mu  = s * (1.f / (float)kD);
  float var = ss * (1.f / (float)kD) - mu * mu;
  float inv = rsqrtf(var + kLnEps);

  float4 gg = ((const float4*)lng)[tid];
  float4 bb = ((const float4*)lnb)[tid];
  float4 o;
  o.x = (g0 - mu) * inv * gg.x + bb.x;
  o.y = (g1 - mu) * inv * gg.y + bb.y;
  o.z = (g2 - mu) * inv * gg.z + bb.z;
  o.w = (g3 - mu) * inv * gg.w + bb.w;

  const int b = n >> 12, l = n & 4095;
  const int cc = tid * 4;
  size_t base = ((size_t)(b * 8192 + 2 * l)) * kD + cc;
  *(float4*)(OUT + base)      = o;
  *(float4*)(OUT + base + kD) = o;
}

// ---------------------------------------------------------------------------
extern "C" void kernel_launch(void* const* d_in, const int* in_sizes, int n_in,
                              void* d_out, int out_size, void* d_ws, size_t ws_size,
                              hipStream_t stream)
{
  (void)in_sizes; (void)n_in; (void)out_size; (void)ws_size;
  const float* x    = (const float*)d_in[0];
  const float* Wq   = (const float*)d_in[1];
  const float* Wk   = (const float*)d_in[2];
  const float* Wv   = (const float*)d_in[3];
  const float* Wo   = (const float*)d_in[4];
  const float* proj = (const float*)d_in[5];
  const float* lng  = (const float*)d_in[6];
  const float* lnb  = (const float*)d_in[7];
  float* out = (float*)d_out;

  // Workspace layout (MB offsets):
  //  0   xb    bf16 [8192,1024]
  //  16  WqkvT bf16 [3072,1024] (Wq/Wk/Wv transposed, stacked)
  //  22  WoT   bf16 [1024,1024] transposed
  //  24  Qb    bf16 [8192,1024] (live until fused_qf_attn)
  //  40  Kb    bf16 (consumed by favor_k; reused as ATTN bf16)
  //  56  VT    bf16 [32 bh][64 d][4096 l]
  //  72  KVP   f32 [512][128*64] 16 MB (dead after kv_reduce; Yb reuses)
  //  136 KFT   bf16 [32 bh][256 m][4096 l]
  //  200 KSP   f32 [512][128]
  //  201 KVT   bf16 [32,80,256]
  //  203 projb bf16 [16,256,64]
  char* ws = (char*)d_ws;
  const size_t MB = 1024 * 1024;
  unsigned short* xb    = (unsigned short*)(ws);
  unsigned short* WqkvT = (unsigned short*)(ws + 16 * MB);
  unsigned short* WoT   = (unsigned short*)(ws + 22 * MB);
  unsigned short* Qb    = (unsigned short*)(ws + 24 * MB);
  unsigned short* Kb    = (unsigned short*)(ws + 40 * MB);
  unsigned short* VT    = (unsigned short*)(ws + 56 * MB);
  float* KVP            = (float*)(ws + 72 * MB);
  unsigned short* KFT   = (unsigned short*)(ws + 136 * MB);
  float* KSP            = (float*)(ws + 200 * MB);
  unsigned short* KVT   = (unsigned short*)(ws + 201 * MB);
  unsigned short* projb = (unsigned short*)(ws + 203 * MB);
  unsigned short* ATTN  = Kb;                       // after favor_k consumed Kb
  unsigned short* Yb    = (unsigned short*)(ws + 72 * MB);  // after KVP dead

  // 1) casts + weight transposes (one launch)
  cast_bf16_kernel<<<(kN * kD) / 1024, 256, 0, stream>>>(x, xb);
  cast_bf16_kernel<<<(kH * kM * kDH) / 1024, 256, 0, stream>>>(proj, projb);
  transpose_cast4_kernel<<<dim3(32, 32, 4), 256, 0, stream>>>(
      Wq, Wk, Wv, Wo, WqkvT, WoT);

  // 2) merged Q+K+V projections (one launch, 1536 blocks = 6/CU)
  gemm_qkv_mfma<<<dim3(24, 64), 256, 0, stream>>>(xb, WqkvT, Qb, Kb, VT);

  // 3) FAVOR-K (stored transposed), then kv / ksum, reduce to KVT'
  favor_k_mfma<<<dim3(32, 32), 256, 0, stream>>>(Kb, projb, KFT);
  kv_mfma<<<dim3(32, 2, 8), 256, 0, stream>>>(KFT, VT, KVP, KSP);
  kv_reduce_kernel<<<32 * 80, 256, 0, stream>>>(KVP, KSP, KVT);

  // 4) fused FAVOR-Q + attention read-out -> bf16 ATTN (QF eliminated)
  fused_qf_attn<<<dim3(32, 32), 256, 0, stream>>>(Qb, projb, KVT, ATTN);

  // 5) output projection (bf16 out)
  gemm_wo_mfma<<<dim3(8, 64), 256, 0, stream>>>(ATTN, WoT, Yb);

  // 6) GELU + LayerNorm + 2x duplicate write
  gelu_ln_kernel<<<kN, 256, 0, stream>>>(Yb, lng, lnb, out);
}

// Round 14
// 323.740 us; speedup vs baseline: 1.0542x; 1.0031x over previous
//
#include <hip/hip_runtime.h>

// Problem constants (fixed by the reference).
static constexpr int kB  = 2;
static constexpr int kL  = 4096;   // source sequence length
static constexpr int kD  = 1024;
static constexpr int kH  = 16;
static constexpr int kDH = 64;
static constexpr int kM  = 256;
static constexpr int kN  = kB * kL;              // 8192 deduplicated rows
static constexpr float kScale    = 0.35355339059327373f;  // DH^-0.25
static constexpr float kInvSqrtM = 0.0625f;               // M^-0.5
static constexpr float kEps   = 1e-6f;
static constexpr float kLnEps = 1e-5f;

typedef __attribute__((ext_vector_type(8))) short short8;   // 8 bf16 (4 VGPRs)
typedef __attribute__((ext_vector_type(4))) float f32x4;

__device__ __forceinline__ float bf2f(unsigned short h) {
  union { unsigned int u; float f; } c;
  c.u = ((unsigned int)h) << 16;
  return c.f;
}
__device__ __forceinline__ unsigned short f2bf(float f) {
  union { float f; unsigned int u; } c;
  c.f = f;
  unsigned int u = c.u;
  u += 0x7fffu + ((u >> 16) & 1u);   // round-to-nearest-even
  return (unsigned short)(u >> 16);
}

// async global->LDS, 16 B per lane; LDS dest = wave-uniform base + lane*16.
__device__ __forceinline__ void gload_lds16(const unsigned short* g,
                                            unsigned short* l) {
  __builtin_amdgcn_global_load_lds(
      (const __attribute__((address_space(1))) unsigned int*)g,
      (__attribute__((address_space(3))) unsigned int*)l, 16, 0, 0);
}

// Bijective XCD-chunked block remap (nwg must be a multiple of 8).
__device__ __forceinline__ void xcd_swizzle(int& bx, int& by) {
  const int nwg = gridDim.x * gridDim.y;
  const int bid = blockIdx.x + gridDim.x * blockIdx.y;
  const int cpx = nwg >> 3;
  const int sb  = (bid & 7) * cpx + (bid >> 3);
  bx = sb % gridDim.x;
  by = sb / gridDim.x;
}

// ---------------------------------------------------------------------------
// casts
// ---------------------------------------------------------------------------
__global__ __launch_bounds__(256) void cast_bf16_kernel(
    const float* __restrict__ in, unsigned short* __restrict__ out)
{
  const int i = blockIdx.x * 256 + threadIdx.x;
  float4 v = ((const float4*)in)[i];
  ushort4 o;
  o.x = f2bf(v.x); o.y = f2bf(v.y); o.z = f2bf(v.z); o.w = f2bf(v.w);
  ((ushort4*)out)[i] = o;
}

// All four weight transposes in one launch. z in {0,1,2}: Wq/Wk/Wv into
// WqkvT[3072][1024] at row offset z*1024; z==3: Wo into WoT.
__global__ __launch_bounds__(256) void transpose_cast4_kernel(
    const float* __restrict__ W0, const float* __restrict__ W1,
    const float* __restrict__ W2, const float* __restrict__ W3,
    unsigned short* __restrict__ WqkvT, unsigned short* __restrict__ WoT)
{
  __shared__ float tile[32][33];
  const int z = blockIdx.z;
  const float* W = (z == 0) ? W0 : (z == 1) ? W1 : (z == 2) ? W2 : W3;
  unsigned short* WT = (z < 3) ? (WqkvT + (size_t)z * kD * kD) : WoT;
  const int n0 = blockIdx.x * 32, k0 = blockIdx.y * 32;
  const int t = threadIdx.x, kk = t >> 5, nn = t & 31;
#pragma unroll
  for (int i = 0; i < 4; ++i)
    tile[kk + i * 8][nn] = W[(size_t)(k0 + kk + i * 8) * kD + n0 + nn];
  __syncthreads();
#pragma unroll
  for (int i = 0; i < 4; ++i)
    WT[(size_t)(n0 + kk + i * 8) * kD + k0 + nn] = f2bf(tile[nn][kk + i * 8]);
}

// ---------------------------------------------------------------------------
// BK=64 K-loop GEMM body (r12-proven: bank-conflict-free). 16 K-steps.
// Global SOURCE pre-swizzled per-lane (chunk ^= row&7), LDS dest linear,
// fragment reads apply the same XOR. LDS[row][cs] = global[row][cs^(row&7)].
// ---------------------------------------------------------------------------
#define GEMM_BK64_BODY(Aptr, Bptr, arow0, bcol0)                              \
  const int lrow = lane >> 3;                                                 \
  const int lcol = ((lane & 7) ^ lrow) * 8; /* swizzled global chunk */       \
  f32x4 acc[4][4];                                                            \
  _Pragma("unroll")                                                           \
  for (int i = 0; i < 4; ++i)                                                 \
    _Pragma("unroll")                                                         \
    for (int j = 0; j < 4; ++j) acc[i][j] = (f32x4)0.f;                       \
  for (int k0 = 0; k0 < kD; k0 += 64) {                                       \
    _Pragma("unroll")                                                         \
    for (int i = 0; i < 4; ++i) {                                             \
      const int r0 = w * 32 + i * 8;                                          \
      gload_lds16(&Aptr[(size_t)(arow0 + r0 + lrow) * kD + k0 + lcol],        \
                  &As[r0 * 64]);                                              \
      gload_lds16(&Bptr[(size_t)(bcol0 + r0 + lrow) * kD + k0 + lcol],        \
                  &Bs[r0 * 64]);                                              \
    }                                                                         \
    __syncthreads();                                                          \
    _Pragma("unroll")                                                         \
    for (int ks = 0; ks < 2; ++ks) {                                          \
      short8 av[4], bv[4];                                                    \
      const int ch = ks * 4 + q;                                              \
      _Pragma("unroll")                                                       \
      for (int i = 0; i < 4; ++i)                                             \
        av[i] = *(const short8*)&As[(wr + i * 16 + c) * 64 +                  \
                                    ((ch ^ (c & 7)) * 8)];                    \
      _Pragma("unroll")                                                       \
      for (int j = 0; j < 4; ++j)                                             \
        bv[j] = *(const short8*)&Bs[(wc + j * 16 + c) * 64 +                  \
                                    ((ch ^ (c & 7)) * 8)];                    \
      _Pragma("unroll")                                                       \
      for (int i = 0; i < 4; ++i)                                             \
        _Pragma("unroll")                                                     \
        for (int j = 0; j < 4; ++j)                                           \
          acc[i][j] = __builtin_amdgcn_mfma_f32_16x16x32_bf16(                \
              av[i], bv[j], acc[i][j], 0, 0, 0);                              \
    }                                                                         \
    __syncthreads();                                                          \
  }

// ---------------------------------------------------------------------------
// Merged Q+K+V projection GEMM (BK=64 swizzled, XCD-swizzled). Grid 24x64.
// bx<16: QK path; bx>=16: VT path (swapped operands, native row-major out).
// ---------------------------------------------------------------------------
__global__ __launch_bounds__(256) void gemm_qkv_mfma(
    const unsigned short* __restrict__ xb, const unsigned short* __restrict__ WqkvT,
    unsigned short* __restrict__ Qb, unsigned short* __restrict__ Kb,
    unsigned short* __restrict__ VT)
{
  __shared__ unsigned short As[128 * 64];   // 16 KB
  __shared__ unsigned short Bs[128 * 64];   // 16 KB
  const int tid = threadIdx.x, lane = tid & 63, w = tid >> 6;
  const int q = lane >> 4, c = lane & 15;
  const int wr = (w >> 1) * 64, wc = (w & 1) * 64;
  int bx, by; xcd_swizzle(bx, by);
  const bool isv = (bx >= 16);
  const unsigned short* WvT = WqkvT + (size_t)2 * kD * kD;
  const unsigned short* Ap = isv ? WvT : xb;
  const unsigned short* Bp = isv ? xb : WqkvT;
  const int arow0 = isv ? (bx - 16) * 128 : by * 128;
  const int bcol0 = isv ? by * 128 : bx * 128;

  GEMM_BK64_BODY(Ap, Bp, arow0, bcol0)

  if (!isv) {
    unsigned short* O = (bcol0 < 1024) ? Qb : Kb;
    const int cl0 = bcol0 & 1023;
#pragma unroll
    for (int i = 0; i < 4; ++i)
#pragma unroll
      for (int j = 0; j < 4; ++j)
#pragma unroll
        for (int r = 0; r < 4; ++r) {
          const int row = arow0 + wr + i * 16 + q * 4 + r;
          const int col = cl0 + wc + j * 16 + c;
          O[(size_t)row * kD + col] = f2bf(kScale * acc[i][j][r]);
        }
  } else {
    // row = output V-channel (h*64+d), col = b*4096 + l
#pragma unroll
    for (int i = 0; i < 4; ++i)
#pragma unroll
      for (int j = 0; j < 4; ++j)
#pragma unroll
        for (int r = 0; r < 4; ++r) {
          const int row = arow0 + wr + i * 16 + q * 4 + r;
          const int col = bcol0 + wc + j * 16 + c;
          const int bq = col >> 12, l = col & 4095;
          const int h = row >> 6, d = row & 63;
          VT[((size_t)((bq * 16 + h) * 64 + d)) * (size_t)kL + l] =
              f2bf(acc[i][j][r]);
        }
  }
}

// ---------------------------------------------------------------------------
// Wo projection GEMM, 128x64 tile (grid 16x64 = 1024 blocks, 4 blocks/CU+).
// BK=64 swizzled staging; wave w owns rows [w*32, w*32+32) x all 64 cols.
// bf16 row-major out (Yb).
// ---------------------------------------------------------------------------
__global__ __launch_bounds__(256) void gemm_wo_mfma(
    const unsigned short* __restrict__ A, const unsigned short* __restrict__ BT,
    unsigned short* __restrict__ Yb)
{
  __shared__ unsigned short As[128 * 64];   // 16 KB
  __shared__ unsigned short Bs[64 * 64];    // 8 KB
  const int tid = threadIdx.x, lane = tid & 63, w = tid >> 6;
  const int q = lane >> 4, c = lane & 15;
  int bx, by; xcd_swizzle(bx, by);
  const int row0 = by * 128, col0 = bx * 64;
  const int lrow = lane >> 3;
  const int lcol = ((lane & 7) ^ lrow) * 8;   // swizzled global chunk

  f32x4 acc[2][4];
#pragma unroll
  for (int i = 0; i < 2; ++i)
#pragma unroll
    for (int j = 0; j < 4; ++j) acc[i][j] = (f32x4)0.f;

  for (int k0 = 0; k0 < kD; k0 += 64) {
#pragma unroll
    for (int i = 0; i < 4; ++i) {
      const int r0 = w * 32 + i * 8;
      gload_lds16(&A[(size_t)(row0 + r0 + lrow) * kD + k0 + lcol], &As[r0 * 64]);
    }
#pragma unroll
    for (int i = 0; i < 2; ++i) {
      const int r0 = w * 16 + i * 8;
      gload_lds16(&BT[(size_t)(col0 + r0 + lrow) * kD + k0 + lcol], &Bs[r0 * 64]);
    }
    __syncthreads();
#pragma unroll
    for (int ks = 0; ks < 2; ++ks) {
      short8 av[2], bv[4];
      const int ch = ks * 4 + q;
#pragma unroll
      for (int i = 0; i < 2; ++i)
        av[i] = *(const short8*)&As[(w * 32 + i * 16 + c) * 64 +
                                    ((ch ^ (c & 7)) * 8)];
#pragma unroll
      for (int j = 0; j < 4; ++j)
        bv[j] = *(const short8*)&Bs[(j * 16 + c) * 64 + ((ch ^ (c & 7)) * 8)];
#pragma unroll
      for (int i = 0; i < 2; ++i)
#pragma unroll
        for (int j = 0; j < 4; ++j)
          acc[i][j] = __builtin_amdgcn_mfma_f32_16x16x32_bf16(
              av[i], bv[j], acc[i][j], 0, 0, 0);
    }
    __syncthreads();
  }

#pragma unroll
  for (int i = 0; i < 2; ++i)
#pragma unroll
    for (int j = 0; j < 4; ++j)
#pragma unroll
      for (int r = 0; r < 4; ++r) {
        const int row = row0 + w * 32 + i * 16 + q * 4 + r;
        const int col = col0 + j * 16 + c;
        Yb[(size_t)row * kD + col] = f2bf(acc[i][j][r]);
      }
}

// ---------------------------------------------------------------------------
// FAVOR-K via MFMA (r4/r8-proven TRANS=1 path): proj staged in LDS, Tbuf
// aliased onto Us. Stores KFT [bh][m][l] via 64-row LDS chunks. 56,832 B.
// ---------------------------------------------------------------------------
__global__ __launch_bounds__(256) void favor_k_mfma(
    const unsigned short* __restrict__ U, const unsigned short* __restrict__ projb,
    unsigned short* __restrict__ F)
{
  __shared__ unsigned short Us[128 * 72];    // 18.4 KB; reused as Tbuf later
  __shared__ unsigned short Ps[256 * 72];    // 36.9 KB, proj head, pad 72
  __shared__ float diagp[256];
  __shared__ float diag[128];
  unsigned short* Tbuf = Us;                 // alias: 64*136 = 8704 <= 9216
  const int bh = blockIdx.x, b = bh >> 4, h = bh & 15;
  const int l0 = blockIdx.y * 128;
  const int tid = threadIdx.x, lane = tid & 63, w = tid >> 6;
  const int q = lane >> 4, c = lane & 15;
  const int wr = w * 32;

#pragma unroll
  for (int it = 0; it < 4; ++it) {
    int idx = it * 256 + tid;
    int row = idx >> 3, col8 = idx & 7;
    *(uint4*)&Us[row * 72 + col8 * 8] =
        *(const uint4*)&U[((size_t)(b * kL + l0 + row)) * kD + h * kDH + col8 * 8];
  }
#pragma unroll
  for (int it = 0; it < 8; ++it) {
    int idx = it * 256 + tid;
    int row = idx >> 3, col8 = idx & 7;
    *(uint4*)&Ps[row * 72 + col8 * 8] =
        *(const uint4*)&projb[((size_t)(h * kM + row)) * kDH + col8 * 8];
  }
  __syncthreads();

  {
    int row = tid & 127, half = tid >> 7;
    const unsigned short* ur = &Us[row * 72 + half * 32];
    float s = 0.f;
#pragma unroll
    for (int d8 = 0; d8 < 4; ++d8) {
      uint4 raw = *(const uint4*)&ur[d8 * 8];
      const unsigned short* us = (const unsigned short*)&raw;
#pragma unroll
      for (int j = 0; j < 8; ++j) { float v = bf2f(us[j]); s = fmaf(v, v, s); }
    }
    diagp[half * 128 + row] = s;
  }

  f32x4 acc[2][16];
#pragma unroll
  for (int i = 0; i < 2; ++i)
#pragma unroll
    for (int j = 0; j < 16; ++j) acc[i][j] = (f32x4)0.f;

#pragma unroll
  for (int ks = 0; ks < 2; ++ks) {
    short8 av[2];
#pragma unroll
    for (int i = 0; i < 2; ++i)
      av[i] = *(const short8*)&Us[(wr + i * 16 + c) * 72 + ks * 32 + q * 8];
#pragma unroll
    for (int jb = 0; jb < 2; ++jb) {
      short8 bv[8];
#pragma unroll
      for (int jl = 0; jl < 8; ++jl)
        bv[jl] = *(const short8*)&Ps[((jb * 8 + jl) * 16 + c) * 72 + ks * 32 + q * 8];
#pragma unroll
      for (int jl = 0; jl < 8; ++jl)
#pragma unroll
        for (int i = 0; i < 2; ++i)
          acc[i][jb * 8 + jl] = __builtin_amdgcn_mfma_f32_16x16x32_bf16(
              av[i], bv[jl], acc[i][jb * 8 + jl], 0, 0, 0);
    }
  }

  __syncthreads();   // all Us reads complete (required: Tbuf aliases Us)
  if (tid < 128) diag[tid] = 0.5f * (diagp[tid] + diagp[128 + tid]);
  __syncthreads();

#pragma unroll
  for (int i = 0; i < 2; ++i)
#pragma unroll
    for (int r = 0; r < 4; ++r) {
      const int lrow = wr + i * 16 + q * 4 + r;
      float mx = -3.4e38f;
#pragma unroll
      for (int j = 0; j < 16; ++j) mx = fmaxf(mx, acc[i][j][r]);
      mx = fmaxf(mx, __shfl_xor(mx, 1, 64));
      mx = fmaxf(mx, __shfl_xor(mx, 2, 64));
      mx = fmaxf(mx, __shfl_xor(mx, 4, 64));
      mx = fmaxf(mx, __shfl_xor(mx, 8, 64));
      const float base = diag[lrow] + mx;
#pragma unroll
      for (int j = 0; j < 16; ++j)
        acc[i][j][r] = __expf(acc[i][j][r] - base) * kInvSqrtM;
    }

  // LDS-transpose 64-m chunks, store KFT[bh*256 + m][l0..l0+128).
#pragma unroll
  for (int mc = 0; mc < 4; ++mc) {
    __syncthreads();
#pragma unroll
    for (int jl = 0; jl < 4; ++jl) {
      const int jj = mc * 4 + jl;
#pragma unroll
      for (int i = 0; i < 2; ++i) {
        ushort4 o;
        o.x = f2bf(acc[i][jj][0]); o.y = f2bf(acc[i][jj][1]);
        o.z = f2bf(acc[i][jj][2]); o.w = f2bf(acc[i][jj][3]);
        *(ushort4*)&Tbuf[(jl * 16 + c) * 136 + wr + i * 16 + q * 4] = o;
      }
    }
    __syncthreads();
#pragma unroll
    for (int it = 0; it < 4; ++it) {       // 1024 uint4 = 64 rows x 16
      int idx = it * 256 + tid;
      int row = idx >> 4, col8 = idx & 15;
      *(uint4*)&F[((size_t)(bh * kM + mc * 64 + row)) * (size_t)kL +
                  l0 + col8 * 8] = *(const uint4*)&Tbuf[row * 136 + col8 * 8];
    }
  }
}

// ---------------------------------------------------------------------------
// FUSED FAVOR-Q + attention read-out (r11 LDS diet + r14 barrier-free
// Phase B). Wave w writes AND reads only rows [w*32, w*32+32) of qs, so the
// per-chunk __syncthreads() pairs synchronized nothing across waves — they
// are removed; intra-wave LDS write->read ordering is handled by lgkmcnt.
// One barrier remains (after kvs staging). 46,080 B LDS, 3 blocks/CU.
// ---------------------------------------------------------------------------
__global__ __launch_bounds__(256) void fused_qf_attn(
    const unsigned short* __restrict__ U, const unsigned short* __restrict__ projb,
    const unsigned short* __restrict__ KVT, unsigned short* __restrict__ ATTN)
{
  __shared__ unsigned short SA[22016];   // 44,032 B union (see below)
  __shared__ float diagp[256];
  __shared__ float diag[128];
  __shared__ unsigned short ksumS[256];
  unsigned short* Us  = SA;              // [128][72] = 9216   (phase A)
  unsigned short* Ps2 = SA + 9216;       // [128][72] = 9216   (phase A, half)
  unsigned short* kvs = SA;              // [64][264] = 16896  (phase B)
  unsigned short* qs  = SA + 16896;      // [128][40] = 5120   (phase B)
  const int bh = blockIdx.x, b = bh >> 4, h = bh & 15;
  const int l0 = blockIdx.y * 128;
  const int tid = threadIdx.x, lane = tid & 63, w = tid >> 6;
  const int q = lane >> 4, c = lane & 15;
  const int wr = w * 32;

  // --- Phase A: dash + exp, proj staged in two 128-row halves ---
#pragma unroll
  for (int it = 0; it < 4; ++it) {
    int idx = it * 256 + tid;
    int row = idx >> 3, col8 = idx & 7;
    *(uint4*)&Us[row * 72 + col8 * 8] =
        *(const uint4*)&U[((size_t)(b * kL + l0 + row)) * kD + h * kDH + col8 * 8];
  }
#pragma unroll
  for (int it = 0; it < 4; ++it) {       // proj half 0: rows 0..127
    int idx = it * 256 + tid;
    int row = idx >> 3, col8 = idx & 7;
    *(uint4*)&Ps2[row * 72 + col8 * 8] =
        *(const uint4*)&projb[((size_t)(h * kM + row)) * kDH + col8 * 8];
  }
  __syncthreads();

  {
    int row = tid & 127, half = tid >> 7;
    const unsigned short* ur = &Us[row * 72 + half * 32];
    float s = 0.f;
#pragma unroll
    for (int d8 = 0; d8 < 4; ++d8) {
      uint4 raw = *(const uint4*)&ur[d8 * 8];
      const unsigned short* us = (const unsigned short*)&raw;
#pragma unroll
      for (int j = 0; j < 8; ++j) { float v = bf2f(us[j]); s = fmaf(v, v, s); }
    }
    diagp[half * 128 + row] = s;
  }

  f32x4 acc[2][16];
#pragma unroll
  for (int i = 0; i < 2; ++i)
#pragma unroll
    for (int j = 0; j < 16; ++j) acc[i][j] = (f32x4)0.f;

#pragma unroll
  for (int half = 0; half < 2; ++half) {
    if (half == 1) {
      __syncthreads();   // prior Ps2 reads done
#pragma unroll
      for (int it = 0; it < 4; ++it) {   // proj half 1: rows 128..255
        int idx = it * 256 + tid;
        int row = idx >> 3, col8 = idx & 7;
        *(uint4*)&Ps2[row * 72 + col8 * 8] =
            *(const uint4*)&projb[((size_t)(h * kM + 128 + row)) * kDH + col8 * 8];
      }
      __syncthreads();
    }
#pragma unroll
    for (int ks = 0; ks < 2; ++ks) {
      short8 av[2];
#pragma unroll
      for (int i = 0; i < 2; ++i)
        av[i] = *(const short8*)&Us[(wr + i * 16 + c) * 72 + ks * 32 + q * 8];
      short8 bv[8];
#pragma unroll
      for (int jl = 0; jl < 8; ++jl)
        bv[jl] = *(const short8*)&Ps2[(jl * 16 + c) * 72 + ks * 32 + q * 8];
#pragma unroll
      for (int jl = 0; jl < 8; ++jl)
#pragma unroll
        for (int i = 0; i < 2; ++i)
          acc[i][half * 8 + jl] = __builtin_amdgcn_mfma_f32_16x16x32_bf16(
              av[i], bv[jl], acc[i][half * 8 + jl], 0, 0, 0);
    }
  }

  __syncthreads();   // all Us/Ps2 reads complete; alias region reusable
  if (tid < 128) diag[tid] = 0.5f * (diagp[tid] + diagp[128 + tid]);
  // stage kvs: 64 rows x 256 cols = 2048 uint4, 8 per thread
#pragma unroll
  for (int it = 0; it < 8; ++it) {
    int idx = it * 256 + tid;
    int row = idx >> 5, col8 = (idx & 31) * 8;
    *(uint4*)&kvs[row * 264 + col8] =
        *(const uint4*)&KVT[(size_t)bh * (80 * kM) + row * kM + col8];
  }
  // stage ksum row (KVT row 64): 32 uint4
  if (tid < 32)
    *(uint4*)&ksumS[tid * 8] =
        *(const uint4*)&KVT[(size_t)bh * (80 * kM) + 64 * kM + tid * 8];
  __syncthreads();   // diag + kvs + ksum ready (sole Phase B barrier)

  // exp epilogue in registers: acc <- exp(dash - diag - rowmax) * M^-0.5
#pragma unroll
  for (int i = 0; i < 2; ++i)
#pragma unroll
    for (int r = 0; r < 4; ++r) {
      const int lrow = wr + i * 16 + q * 4 + r;
      float mx = -3.4e38f;
#pragma unroll
      for (int j = 0; j < 16; ++j) mx = fmaxf(mx, acc[i][j][r]);
      mx = fmaxf(mx, __shfl_xor(mx, 1, 64));
      mx = fmaxf(mx, __shfl_xor(mx, 2, 64));
      mx = fmaxf(mx, __shfl_xor(mx, 4, 64));
      mx = fmaxf(mx, __shfl_xor(mx, 8, 64));
      const float base = diag[lrow] + mx;
#pragma unroll
      for (int j = 0; j < 16; ++j)
        acc[i][j][r] = __expf(acc[i][j][r] - base) * kInvSqrtM;
    }

  // denominator via VALU + shfl: den[row] = sum_m qf[row][m] * ksum[m]
  float z_[2][4];
#pragma unroll
  for (int i = 0; i < 2; ++i)
#pragma unroll
    for (int r = 0; r < 4; ++r) {
      float d = 0.f;
#pragma unroll
      for (int j = 0; j < 16; ++j)
        d = fmaf(acc[i][j][r], bf2f(ksumS[j * 16 + c]), d);
      d += __shfl_xor(d, 1, 64);
      d += __shfl_xor(d, 2, 64);
      d += __shfl_xor(d, 4, 64);
      d += __shfl_xor(d, 8, 64);
      z_[i][r] = 1.f / (d + kEps);
    }

  // --- Phase B: attn MFMA over 8 m-chunks of 32, BARRIER-FREE (wave-local
  // qs slices; each wave streams through chunks independently) ---
  f32x4 acc2[2][4];
#pragma unroll
  for (int i = 0; i < 2; ++i)
#pragma unroll
    for (int j = 0; j < 4; ++j) acc2[i][j] = (f32x4)0.f;

#pragma unroll
  for (int kk = 0; kk < 8; ++kk) {
#pragma unroll
    for (int i = 0; i < 2; ++i)
#pragma unroll
      for (int jj2 = 0; jj2 < 2; ++jj2) {
        const int jj = kk * 2 + jj2;
#pragma unroll
        for (int r = 0; r < 4; ++r)
          qs[(wr + i * 16 + q * 4 + r) * 40 + jj2 * 16 + c] =
              f2bf(acc[i][jj][r]);
      }
    short8 bv2[4];
#pragma unroll
    for (int j = 0; j < 4; ++j)
      bv2[j] = *(const short8*)&kvs[(j * 16 + c) * 264 + kk * 32 + q * 8];
#pragma unroll
    for (int i = 0; i < 2; ++i) {
      short8 av2 = *(const short8*)&qs[(w * 32 + i * 16 + c) * 40 + q * 8];
#pragma unroll
      for (int j = 0; j < 4; ++j)
        acc2[i][j] = __builtin_amdgcn_mfma_f32_16x16x32_bf16(
            av2, bv2[j], acc2[i][j], 0, 0, 0);
    }
  }

  // epilogue: scale by 1/den, write ATTN
#pragma unroll
  for (int i = 0; i < 2; ++i)
#pragma unroll
    for (int r = 0; r < 4; ++r) {
      const int row = l0 + w * 32 + i * 16 + q * 4 + r;
      const size_t base = ((size_t)(b * kL + row)) * kD + h * kDH;
#pragma unroll
      for (int j = 0; j < 4; ++j)
        ATTN[base + j * 16 + c] = f2bf(acc2[i][j][r] * z_[i][r]);
    }
}

// ---------------------------------------------------------------------------
// kv via MFMA, BK=64 swizzled (r13): per (bh, mtile, split): C[128 m][64 d]
// = KFT tile @ VT tile^T over 512 l, 8 K-steps. ksum from A-fragments.
// ---------------------------------------------------------------------------
__global__ __launch_bounds__(256) void kv_mfma(
    const unsigned short* __restrict__ KFT, const unsigned short* __restrict__ VT,
    float* __restrict__ KVP, float* __restrict__ KSP)
{
  __shared__ unsigned short As[128 * 64];   // 16 KB
  __shared__ unsigned short Bs[64 * 64];    // 8 KB
  const int bh = blockIdx.x, mtile = blockIdx.y, split = blockIdx.z;
  const int tid = threadIdx.x, lane = tid & 63, w = tid >> 6;
  const int q = lane >> 4, c = lane & 15;
  const int l0 = split * 512;
  const unsigned short* Abase = KFT + ((size_t)(bh * kM + mtile * 128)) * kL + l0;
  const unsigned short* Bbase = VT + ((size_t)(bh * kDH)) * kL + l0;
  const int lrow = lane >> 3;
  const int lcol = ((lane & 7) ^ lrow) * 8;   // swizzled global chunk

  f32x4 acc[2][4];
#pragma unroll
  for (int i = 0; i < 2; ++i)
#pragma unroll
    for (int j = 0; j < 4; ++j) acc[i][j] = (f32x4)0.f;
  float ksr[2] = {0.f, 0.f};

  for (int k0 = 0; k0 < 512; k0 += 64) {
#pragma unroll
    for (int i = 0; i < 4; ++i) {
      const int r0 = w * 32 + i * 8;
      gload_lds16(&Abase[(size_t)(r0 + lrow) * kL + k0 + lcol], &As[r0 * 64]);
    }
#pragma unroll
    for (int i = 0; i < 2; ++i) {
      const int r0 = w * 16 + i * 8;
      gload_lds16(&Bbase[(size_t)(r0 + lrow) * kL + k0 + lcol], &Bs[r0 * 64]);
    }
    __syncthreads();
#pragma unroll
    for (int ks = 0; ks < 2; ++ks) {
      short8 av[2], bv[4];
      const int ch = ks * 4 + q;
#pragma unroll
      for (int i = 0; i < 2; ++i) {
        av[i] = *(const short8*)&As[(w * 32 + i * 16 + c) * 64 +
                                    ((ch ^ (c & 7)) * 8)];
#pragma unroll
        for (int e = 0; e < 8; ++e) ksr[i] += bf2f((unsigned short)av[i][e]);
      }
#pragma unroll
      for (int j = 0; j < 4; ++j)
        bv[j] = *(const short8*)&Bs[(j * 16 + c) * 64 + ((ch ^ (c & 7)) * 8)];
#pragma unroll
      for (int i = 0; i < 2; ++i)
#pragma unroll
        for (int j = 0; j < 4; ++j)
          acc[i][j] = __builtin_amdgcn_mfma_f32_16x16x32_bf16(
              av[i], bv[j], acc[i][j], 0, 0, 0);
    }
    __syncthreads();
  }

  const int blk = (bh * 2 + mtile) * 8 + split;
  float* op = KVP + (size_t)blk * (128 * 64);
#pragma unroll
  for (int i = 0; i < 2; ++i)
#pragma unroll
    for (int j = 0; j < 4; ++j)
#pragma unroll
      for (int r = 0; r < 4; ++r)
        op[(w * 32 + i * 16 + q * 4 + r) * 64 + j * 16 + c] = acc[i][j][r];

#pragma unroll
  for (int i = 0; i < 2; ++i) {
    float s = ksr[i];
    s += __shfl_xor(s, 16, 64);
    s += __shfl_xor(s, 32, 64);
    if (q == 0) KSP[blk * 128 + w * 32 + i * 16 + c] = s;
  }
}

// Reduce 8 splits -> KVT' bf16 [bh][80][256]: rows 0..63 = kv^T[d][m],
// row 64 = ksum[m], rows 65..79 = 0 (pad rows kept for layout compat).
__global__ __launch_bounds__(256) void kv_reduce_kernel(
    const float* __restrict__ KVP, const float* __restrict__ KSP,
    unsigned short* __restrict__ KVT)
{
  const int blk = blockIdx.x;            // 32*80
  const int bh = blk / 80, n = blk - bh * 80;
  const int t = threadIdx.x;             // m
  const int mt = t >> 7, ml = t & 127;
  float s = 0.f;
  if (n < 64) {
#pragma unroll
    for (int sp = 0; sp < 8; ++sp)
      s += KVP[((size_t)((bh * 2 + mt) * 8 + sp)) * (128 * 64) + ml * 64 + n];
  } else if (n == 64) {
#pragma unroll
    for (int sp = 0; sp < 8; ++sp)
      s += KSP[((bh * 2 + mt) * 8 + sp) * 128 + ml];
  }
  KVT[(size_t)bh * (80 * kM) + n * kM + t] = f2bf(s);
}

// ---------------------------------------------------------------------------
// GELU (exact) + LayerNorm + 2x nearest-neighbor duplicate write.
// Reads Y as bf16 (written by gemm_wo) — halves the Y round trip.
// ---------------------------------------------------------------------------
__global__ __launch_bounds__(256) void gelu_ln_kernel(
    const unsigned short* __restrict__ Yb, const float* __restrict__ lng,
    const float* __restrict__ lnb, float* __restrict__ OUT)
{
  __shared__ float r1[4], r2[4];
  const int n = blockIdx.x;
  const int tid = threadIdx.x, lane = tid & 63, w = tid >> 6;

  ushort4 yv = ((const ushort4*)(Yb + (size_t)n * kD))[tid];
  float y0 = bf2f(yv.x), y1 = bf2f(yv.y), y2 = bf2f(yv.z), y3 = bf2f(yv.w);
  float g0 = 0.5f * y0 * (1.f + erff(y0 * 0.70710678118654752f));
  float g1 = 0.5f * y1 * (1.f + erff(y1 * 0.70710678118654752f));
  float g2 = 0.5f * y2 * (1.f + erff(y2 * 0.70710678118654752f));
  float g3 = 0.5f * y3 * (1.f + erff(y3 * 0.70710678118654752f));

  float s  = (g0 + g1) + (g2 + g3);
  float ss = (g0 * g0 + g1 * g1) + (g2 * g2 + g3 * g3);
#pragma unroll
  for (int off = 32; off; off >>= 1) {
    s  += __shfl_xor(s, off, 64);
    ss += __shfl_xor(ss, off, 64);
  }
  if (lane == 0) { r1[w] = s; r2[w] = ss; }
  __syncthreads();
  s  = (r1[0] + r1[1]) + (r1[2] + r1[3]);
  ss = (r2[0] + r2[1]) + (r2[2] + r2[3]);
  float mu  = s * (1.f / (float)kD);
  float var = ss * (1.f / (float)kD) - mu * mu;
  float inv = rsqrtf(var + kLnEps);

  float4 gg = ((const float4*)lng)[tid];
  float4 bb = ((const float4*)lnb)[tid];
  float4 o;
  o.x = (g0 - mu) * inv * gg.x + bb.x;
  o.y = (g1 - mu) * inv * gg.y + bb.y;
  o.z = (g2 - mu) * inv * gg.z + bb.z;
  o.w = (g3 - mu) * inv * gg.w + bb.w;

  const int b = n >> 12, l = n & 4095;
  const int cc = tid * 4;
  size_t base = ((size_t)(b * 8192 + 2 * l)) * kD + cc;
  *(float4*)(OUT + base)      = o;
  *(float4*)(OUT + base + kD) = o;
}

// ---------------------------------------------------------------------------
extern "C" void kernel_launch(void* const* d_in, const int* in_sizes, int n_in,
                              void* d_out, int out_size, void* d_ws, size_t ws_size,
                              hipStream_t stream)
{
  (void)in_sizes; (void)n_in; (void)out_size; (void)ws_size;
  const float* x    = (const float*)d_in[0];
  const float* Wq   = (const float*)d_in[1];
  const float* Wk   = (const float*)d_in[2];
  const float* Wv   = (const float*)d_in[3];
  const float* Wo   = (const float*)d_in[4];
  const float* proj = (const float*)d_in[5];
  const float* lng  = (const float*)d_in[6];
  const float* lnb  = (const float*)d_in[7];
  float* out = (float*)d_out;

  // Workspace layout (MB offsets):
  //  0   xb    bf16 [8192,1024]
  //  16  WqkvT bf16 [3072,1024] (Wq/Wk/Wv transposed, stacked)
  //  22  WoT   bf16 [1024,1024] transposed
  //  24  Qb    bf16 [8192,1024] (live until fused_qf_attn)
  //  40  Kb    bf16 (consumed by favor_k; reused as ATTN bf16)
  //  56  VT    bf16 [32 bh][64 d][4096 l]
  //  72  KVP   f32 [512][128*64] 16 MB (dead after kv_reduce; Yb reuses)
  //  136 KFT   bf16 [32 bh][256 m][4096 l]
  //  200 KSP   f32 [512][128]
  //  201 KVT   bf16 [32,80,256]
  //  203 projb bf16 [16,256,64]
  char* ws = (char*)d_ws;
  const size_t MB = 1024 * 1024;
  unsigned short* xb    = (unsigned short*)(ws);
  unsigned short* WqkvT = (unsigned short*)(ws + 16 * MB);
  unsigned short* WoT   = (unsigned short*)(ws + 22 * MB);
  unsigned short* Qb    = (unsigned short*)(ws + 24 * MB);
  unsigned short* Kb    = (unsigned short*)(ws + 40 * MB);
  unsigned short* VT    = (unsigned short*)(ws + 56 * MB);
  float* KVP            = (float*)(ws + 72 * MB);
  unsigned short* KFT   = (unsigned short*)(ws + 136 * MB);
  float* KSP            = (float*)(ws + 200 * MB);
  unsigned short* KVT   = (unsigned short*)(ws + 201 * MB);
  unsigned short* projb = (unsigned short*)(ws + 203 * MB);
  unsigned short* ATTN  = Kb;                       // after favor_k consumed Kb
  unsigned short* Yb    = (unsigned short*)(ws + 72 * MB);  // after KVP dead

  // 1) casts + weight transposes (one launch)
  cast_bf16_kernel<<<(kN * kD) / 1024, 256, 0, stream>>>(x, xb);
  cast_bf16_kernel<<<(kH * kM * kDH) / 1024, 256, 0, stream>>>(proj, projb);
  transpose_cast4_kernel<<<dim3(32, 32, 4), 256, 0, stream>>>(
      Wq, Wk, Wv, Wo, WqkvT, WoT);

  // 2) merged Q+K+V projections (one launch, 1536 blocks = 6/CU)
  gemm_qkv_mfma<<<dim3(24, 64), 256, 0, stream>>>(xb, WqkvT, Qb, Kb, VT);

  // 3) FAVOR-K (stored transposed), then kv / ksum, reduce to KVT'
  favor_k_mfma<<<dim3(32, 32), 256, 0, stream>>>(Kb, projb, KFT);
  kv_mfma<<<dim3(32, 2, 8), 256, 0, stream>>>(KFT, VT, KVP, KSP);
  kv_reduce_kernel<<<32 * 80, 256, 0, stream>>>(KVP, KSP, KVT);

  // 4) fused FAVOR-Q + attention read-out -> bf16 ATTN (QF eliminated)
  fused_qf_attn<<<dim3(32, 32), 256, 0, stream>>>(Qb, projb, KVT, ATTN);

  // 5) output projection (bf16 out, 128x64 tiles, 1024 blocks)
  gemm_wo_mfma<<<dim3(16, 64), 256, 0, stream>>>(ATTN, WoT, Yb);

  // 6) GELU + LayerNorm + 2x duplicate write
  gelu_ln_kernel<<<kN, 256, 0, stream>>>(Yb, lng, lnb, out);
}

// Round 15
// 317.639 us; speedup vs baseline: 1.0744x; 1.0192x over previous
//
#include <hip/hip_runtime.h>

// Problem constants (fixed by the reference).
static constexpr int kB  = 2;
static constexpr int kL  = 4096;   // source sequence length
static constexpr int kD  = 1024;
static constexpr int kH  = 16;
static constexpr int kDH = 64;
static constexpr int kM  = 256;
static constexpr int kN  = kB * kL;              // 8192 deduplicated rows
static constexpr float kScale    = 0.35355339059327373f;  // DH^-0.25
static constexpr float kInvSqrtM = 0.0625f;               // M^-0.5
static constexpr float kEps   = 1e-6f;
static constexpr float kLnEps = 1e-5f;

typedef __attribute__((ext_vector_type(8))) short short8;   // 8 bf16 (4 VGPRs)
typedef __attribute__((ext_vector_type(4))) float f32x4;

__device__ __forceinline__ float bf2f(unsigned short h) {
  union { unsigned int u; float f; } c;
  c.u = ((unsigned int)h) << 16;
  return c.f;
}
__device__ __forceinline__ unsigned short f2bf(float f) {
  union { float f; unsigned int u; } c;
  c.f = f;
  unsigned int u = c.u;
  u += 0x7fffu + ((u >> 16) & 1u);   // round-to-nearest-even
  return (unsigned short)(u >> 16);
}

// async global->LDS, 16 B per lane; LDS dest = wave-uniform base + lane*16.
__device__ __forceinline__ void gload_lds16(const unsigned short* g,
                                            unsigned short* l) {
  __builtin_amdgcn_global_load_lds(
      (const __attribute__((address_space(1))) unsigned int*)g,
      (__attribute__((address_space(3))) unsigned int*)l, 16, 0, 0);
}

// Bijective XCD-chunked block remap (nwg must be a multiple of 8).
__device__ __forceinline__ void xcd_swizzle(int& bx, int& by) {
  const int nwg = gridDim.x * gridDim.y;
  const int bid = blockIdx.x + gridDim.x * blockIdx.y;
  const int cpx = nwg >> 3;
  const int sb  = (bid & 7) * cpx + (bid >> 3);
  bx = sb % gridDim.x;
  by = sb / gridDim.x;
}

// ---------------------------------------------------------------------------
// casts
// ---------------------------------------------------------------------------
__global__ __launch_bounds__(256) void cast_bf16_kernel(
    const float* __restrict__ in, unsigned short* __restrict__ out)
{
  const int i = blockIdx.x * 256 + threadIdx.x;
  float4 v = ((const float4*)in)[i];
  ushort4 o;
  o.x = f2bf(v.x); o.y = f2bf(v.y); o.z = f2bf(v.z); o.w = f2bf(v.w);
  ((ushort4*)out)[i] = o;
}

// All four weight transposes in one launch. z in {0,1,2}: Wq/Wk/Wv into
// WqkvT[3072][1024] at row offset z*1024; z==3: Wo into WoT.
__global__ __launch_bounds__(256) void transpose_cast4_kernel(
    const float* __restrict__ W0, const float* __restrict__ W1,
    const float* __restrict__ W2, const float* __restrict__ W3,
    unsigned short* __restrict__ WqkvT, unsigned short* __restrict__ WoT)
{
  __shared__ float tile[32][33];
  const int z = blockIdx.z;
  const float* W = (z == 0) ? W0 : (z == 1) ? W1 : (z == 2) ? W2 : W3;
  unsigned short* WT = (z < 3) ? (WqkvT + (size_t)z * kD * kD) : WoT;
  const int n0 = blockIdx.x * 32, k0 = blockIdx.y * 32;
  const int t = threadIdx.x, kk = t >> 5, nn = t & 31;
#pragma unroll
  for (int i = 0; i < 4; ++i)
    tile[kk + i * 8][nn] = W[(size_t)(k0 + kk + i * 8) * kD + n0 + nn];
  __syncthreads();
#pragma unroll
  for (int i = 0; i < 4; ++i)
    WT[(size_t)(n0 + kk + i * 8) * kD + k0 + nn] = f2bf(tile[nn][kk + i * 8]);
}

// ---------------------------------------------------------------------------
// BK=64 K-loop GEMM body (r12-proven: bank-conflict-free). 16 K-steps.
// Global SOURCE pre-swizzled per-lane (chunk ^= row&7), LDS dest linear,
// fragment reads apply the same XOR. LDS[row][cs] = global[row][cs^(row&7)].
// ---------------------------------------------------------------------------
#define GEMM_BK64_BODY(Aptr, Bptr, arow0, bcol0)                              \
  const int lrow = lane >> 3;                                                 \
  const int lcol = ((lane & 7) ^ lrow) * 8; /* swizzled global chunk */       \
  f32x4 acc[4][4];                                                            \
  _Pragma("unroll")                                                           \
  for (int i = 0; i < 4; ++i)                                                 \
    _Pragma("unroll")                                                         \
    for (int j = 0; j < 4; ++j) acc[i][j] = (f32x4)0.f;                       \
  for (int k0 = 0; k0 < kD; k0 += 64) {                                       \
    _Pragma("unroll")                                                         \
    for (int i = 0; i < 4; ++i) {                                             \
      const int r0 = w * 32 + i * 8;                                          \
      gload_lds16(&Aptr[(size_t)(arow0 + r0 + lrow) * kD + k0 + lcol],        \
                  &As[r0 * 64]);                                              \
      gload_lds16(&Bptr[(size_t)(bcol0 + r0 + lrow) * kD + k0 + lcol],        \
                  &Bs[r0 * 64]);                                              \
    }                                                                         \
    __syncthreads();                                                          \
    _Pragma("unroll")                                                         \
    for (int ks = 0; ks < 2; ++ks) {                                          \
      short8 av[4], bv[4];                                                    \
      const int ch = ks * 4 + q;                                              \
      _Pragma("unroll")                                                       \
      for (int i = 0; i < 4; ++i)                                             \
        av[i] = *(const short8*)&As[(wr + i * 16 + c) * 64 +                  \
                                    ((ch ^ (c & 7)) * 8)];                    \
      _Pragma("unroll")                                                       \
      for (int j = 0; j < 4; ++j)                                             \
        bv[j] = *(const short8*)&Bs[(wc + j * 16 + c) * 64 +                  \
                                    ((ch ^ (c & 7)) * 8)];                    \
      _Pragma("unroll")                                                       \
      for (int i = 0; i < 4; ++i)                                             \
        _Pragma("unroll")                                                     \
        for (int j = 0; j < 4; ++j)                                           \
          acc[i][j] = __builtin_amdgcn_mfma_f32_16x16x32_bf16(                \
              av[i], bv[j], acc[i][j], 0, 0, 0);                              \
    }                                                                         \
    __syncthreads();                                                          \
  }

// ---------------------------------------------------------------------------
// Merged Q+K+V projection GEMM (BK=64 swizzled, XCD-swizzled). Grid 24x64.
// bx<16: QK path; bx>=16: VT path (swapped operands, native row-major out).
// ---------------------------------------------------------------------------
__global__ __launch_bounds__(256) void gemm_qkv_mfma(
    const unsigned short* __restrict__ xb, const unsigned short* __restrict__ WqkvT,
    unsigned short* __restrict__ Qb, unsigned short* __restrict__ Kb,
    unsigned short* __restrict__ VT)
{
  __shared__ unsigned short As[128 * 64];   // 16 KB
  __shared__ unsigned short Bs[128 * 64];   // 16 KB
  const int tid = threadIdx.x, lane = tid & 63, w = tid >> 6;
  const int q = lane >> 4, c = lane & 15;
  const int wr = (w >> 1) * 64, wc = (w & 1) * 64;
  int bx, by; xcd_swizzle(bx, by);
  const bool isv = (bx >= 16);
  const unsigned short* WvT = WqkvT + (size_t)2 * kD * kD;
  const unsigned short* Ap = isv ? WvT : xb;
  const unsigned short* Bp = isv ? xb : WqkvT;
  const int arow0 = isv ? (bx - 16) * 128 : by * 128;
  const int bcol0 = isv ? by * 128 : bx * 128;

  GEMM_BK64_BODY(Ap, Bp, arow0, bcol0)

  if (!isv) {
    unsigned short* O = (bcol0 < 1024) ? Qb : Kb;
    const int cl0 = bcol0 & 1023;
#pragma unroll
    for (int i = 0; i < 4; ++i)
#pragma unroll
      for (int j = 0; j < 4; ++j)
#pragma unroll
        for (int r = 0; r < 4; ++r) {
          const int row = arow0 + wr + i * 16 + q * 4 + r;
          const int col = cl0 + wc + j * 16 + c;
          O[(size_t)row * kD + col] = f2bf(kScale * acc[i][j][r]);
        }
  } else {
    // row = output V-channel (h*64+d), col = b*4096 + l
#pragma unroll
    for (int i = 0; i < 4; ++i)
#pragma unroll
      for (int j = 0; j < 4; ++j)
#pragma unroll
        for (int r = 0; r < 4; ++r) {
          const int row = arow0 + wr + i * 16 + q * 4 + r;
          const int col = bcol0 + wc + j * 16 + c;
          const int bq = col >> 12, l = col & 4095;
          const int h = row >> 6, d = row & 63;
          VT[((size_t)((bq * 16 + h) * 64 + d)) * (size_t)kL + l] =
              f2bf(acc[i][j][r]);
        }
  }
}

// ---------------------------------------------------------------------------
// Wo projection GEMM, 128x64 tile (grid 16x64 = 1024 blocks).
// BK=64 swizzled staging; wave w owns rows [w*32, w*32+32) x all 64 cols.
// bf16 row-major out (Yb).
// ---------------------------------------------------------------------------
__global__ __launch_bounds__(256) void gemm_wo_mfma(
    const unsigned short* __restrict__ A, const unsigned short* __restrict__ BT,
    unsigned short* __restrict__ Yb)
{
  __shared__ unsigned short As[128 * 64];   // 16 KB
  __shared__ unsigned short Bs[64 * 64];    // 8 KB
  const int tid = threadIdx.x, lane = tid & 63, w = tid >> 6;
  const int q = lane >> 4, c = lane & 15;
  int bx, by; xcd_swizzle(bx, by);
  const int row0 = by * 128, col0 = bx * 64;
  const int lrow = lane >> 3;
  const int lcol = ((lane & 7) ^ lrow) * 8;   // swizzled global chunk

  f32x4 acc[2][4];
#pragma unroll
  for (int i = 0; i < 2; ++i)
#pragma unroll
    for (int j = 0; j < 4; ++j) acc[i][j] = (f32x4)0.f;

  for (int k0 = 0; k0 < kD; k0 += 64) {
#pragma unroll
    for (int i = 0; i < 4; ++i) {
      const int r0 = w * 32 + i * 8;
      gload_lds16(&A[(size_t)(row0 + r0 + lrow) * kD + k0 + lcol], &As[r0 * 64]);
    }
#pragma unroll
    for (int i = 0; i < 2; ++i) {
      const int r0 = w * 16 + i * 8;
      gload_lds16(&BT[(size_t)(col0 + r0 + lrow) * kD + k0 + lcol], &Bs[r0 * 64]);
    }
    __syncthreads();
#pragma unroll
    for (int ks = 0; ks < 2; ++ks) {
      short8 av[2], bv[4];
      const int ch = ks * 4 + q;
#pragma unroll
      for (int i = 0; i < 2; ++i)
        av[i] = *(const short8*)&As[(w * 32 + i * 16 + c) * 64 +
                                    ((ch ^ (c & 7)) * 8)];
#pragma unroll
      for (int j = 0; j < 4; ++j)
        bv[j] = *(const short8*)&Bs[(j * 16 + c) * 64 + ((ch ^ (c & 7)) * 8)];
#pragma unroll
      for (int i = 0; i < 2; ++i)
#pragma unroll
        for (int j = 0; j < 4; ++j)
          acc[i][j] = __builtin_amdgcn_mfma_f32_16x16x32_bf16(
              av[i], bv[j], acc[i][j], 0, 0, 0);
    }
    __syncthreads();
  }

#pragma unroll
  for (int i = 0; i < 2; ++i)
#pragma unroll
    for (int j = 0; j < 4; ++j)
#pragma unroll
      for (int r = 0; r < 4; ++r) {
        const int row = row0 + w * 32 + i * 16 + q * 4 + r;
        const int col = col0 + j * 16 + c;
        Yb[(size_t)row * kD + col] = f2bf(acc[i][j][r]);
      }
}

// ---------------------------------------------------------------------------
// FAVOR-K via MFMA, r15 LDS diet (r11 recipe applied): proj staged in two
// [128][72] halves through Ps2 instead of one [256][72] block. LDS drops
// 56,832 -> 38,400 B (Us 18,432 + Ps2 18,432 + diag 1,536), 2 -> 4
// blocks/CU LDS-wise. Tbuf still aliases Us (dead after the MFMA loop).
// Stores KFT [bh][m][l] via 64-row LDS chunks (unchanged epilogue).
// ---------------------------------------------------------------------------
__global__ __launch_bounds__(256) void favor_k_mfma(
    const unsigned short* __restrict__ U, const unsigned short* __restrict__ projb,
    unsigned short* __restrict__ F)
{
  __shared__ unsigned short Us[128 * 72];    // 18.4 KB; reused as Tbuf later
  __shared__ unsigned short Ps2[128 * 72];   // 18.4 KB, proj half, pad 72
  __shared__ float diagp[256];
  __shared__ float diag[128];
  unsigned short* Tbuf = Us;                 // alias: 64*136 = 8704 <= 9216
  const int bh = blockIdx.x, b = bh >> 4, h = bh & 15;
  const int l0 = blockIdx.y * 128;
  const int tid = threadIdx.x, lane = tid & 63, w = tid >> 6;
  const int q = lane >> 4, c = lane & 15;
  const int wr = w * 32;

  // stage U tile + proj half 0
#pragma unroll
  for (int it = 0; it < 4; ++it) {
    int idx = it * 256 + tid;
    int row = idx >> 3, col8 = idx & 7;
    *(uint4*)&Us[row * 72 + col8 * 8] =
        *(const uint4*)&U[((size_t)(b * kL + l0 + row)) * kD + h * kDH + col8 * 8];
  }
#pragma unroll
  for (int it = 0; it < 4; ++it) {       // proj rows 0..127
    int idx = it * 256 + tid;
    int row = idx >> 3, col8 = idx & 7;
    *(uint4*)&Ps2[row * 72 + col8 * 8] =
        *(const uint4*)&projb[((size_t)(h * kM + row)) * kDH + col8 * 8];
  }
  __syncthreads();

  {
    int row = tid & 127, half = tid >> 7;
    const unsigned short* ur = &Us[row * 72 + half * 32];
    float s = 0.f;
#pragma unroll
    for (int d8 = 0; d8 < 4; ++d8) {
      uint4 raw = *(const uint4*)&ur[d8 * 8];
      const unsigned short* us = (const unsigned short*)&raw;
#pragma unroll
      for (int j = 0; j < 8; ++j) { float v = bf2f(us[j]); s = fmaf(v, v, s); }
    }
    diagp[half * 128 + row] = s;
  }

  f32x4 acc[2][16];
#pragma unroll
  for (int i = 0; i < 2; ++i)
#pragma unroll
    for (int j = 0; j < 16; ++j) acc[i][j] = (f32x4)0.f;

#pragma unroll
  for (int half = 0; half < 2; ++half) {
    if (half == 1) {
      __syncthreads();   // prior Ps2 reads done
#pragma unroll
      for (int it = 0; it < 4; ++it) {   // proj rows 128..255
        int idx = it * 256 + tid;
        int row = idx >> 3, col8 = idx & 7;
        *(uint4*)&Ps2[row * 72 + col8 * 8] =
            *(const uint4*)&projb[((size_t)(h * kM + 128 + row)) * kDH + col8 * 8];
      }
      __syncthreads();
    }
#pragma unroll
    for (int ks = 0; ks < 2; ++ks) {
      short8 av[2];
#pragma unroll
      for (int i = 0; i < 2; ++i)
        av[i] = *(const short8*)&Us[(wr + i * 16 + c) * 72 + ks * 32 + q * 8];
      short8 bv[8];
#pragma unroll
      for (int jl = 0; jl < 8; ++jl)
        bv[jl] = *(const short8*)&Ps2[(jl * 16 + c) * 72 + ks * 32 + q * 8];
#pragma unroll
      for (int jl = 0; jl < 8; ++jl)
#pragma unroll
        for (int i = 0; i < 2; ++i)
          acc[i][half * 8 + jl] = __builtin_amdgcn_mfma_f32_16x16x32_bf16(
              av[i], bv[jl], acc[i][half * 8 + jl], 0, 0, 0);
    }
  }

  __syncthreads();   // all Us reads complete (required: Tbuf aliases Us)
  if (tid < 128) diag[tid] = 0.5f * (diagp[tid] + diagp[128 + tid]);
  __syncthreads();

#pragma unroll
  for (int i = 0; i < 2; ++i)
#pragma unroll
    for (int r = 0; r < 4; ++r) {
      const int lrow2 = wr + i * 16 + q * 4 + r;
      float mx = -3.4e38f;
#pragma unroll
      for (int j = 0; j < 16; ++j) mx = fmaxf(mx, acc[i][j][r]);
      mx = fmaxf(mx, __shfl_xor(mx, 1, 64));
      mx = fmaxf(mx, __shfl_xor(mx, 2, 64));
      mx = fmaxf(mx, __shfl_xor(mx, 4, 64));
      mx = fmaxf(mx, __shfl_xor(mx, 8, 64));
      const float base = diag[lrow2] + mx;
#pragma unroll
      for (int j = 0; j < 16; ++j)
        acc[i][j][r] = __expf(acc[i][j][r] - base) * kInvSqrtM;
    }

  // LDS-transpose 64-m chunks, store KFT[bh*256 + m][l0..l0+128).
#pragma unroll
  for (int mc = 0; mc < 4; ++mc) {
    __syncthreads();
#pragma unroll
    for (int jl = 0; jl < 4; ++jl) {
      const int jj = mc * 4 + jl;
#pragma unroll
      for (int i = 0; i < 2; ++i) {
        ushort4 o;
        o.x = f2bf(acc[i][jj][0]); o.y = f2bf(acc[i][jj][1]);
        o.z = f2bf(acc[i][jj][2]); o.w = f2bf(acc[i][jj][3]);
        *(ushort4*)&Tbuf[(jl * 16 + c) * 136 + wr + i * 16 + q * 4] = o;
      }
    }
    __syncthreads();
#pragma unroll
    for (int it = 0; it < 4; ++it) {       // 1024 uint4 = 64 rows x 16
      int idx = it * 256 + tid;
      int row = idx >> 4, col8 = idx & 15;
      *(uint4*)&F[((size_t)(bh * kM + mc * 64 + row)) * (size_t)kL +
                  l0 + col8 * 8] = *(const uint4*)&Tbuf[row * 136 + col8 * 8];
    }
  }
}

// ---------------------------------------------------------------------------
// FUSED FAVOR-Q + attention read-out (r11 LDS diet + r14 barrier-free
// Phase B; both verified). 46,080 B LDS, 3 blocks/CU.
// ---------------------------------------------------------------------------
__global__ __launch_bounds__(256) void fused_qf_attn(
    const unsigned short* __restrict__ U, const unsigned short* __restrict__ projb,
    const unsigned short* __restrict__ KVT, unsigned short* __restrict__ ATTN)
{
  __shared__ unsigned short SA[22016];   // 44,032 B union (see below)
  __shared__ float diagp[256];
  __shared__ float diag[128];
  __shared__ unsigned short ksumS[256];
  unsigned short* Us  = SA;              // [128][72] = 9216   (phase A)
  unsigned short* Ps2 = SA + 9216;       // [128][72] = 9216   (phase A, half)
  unsigned short* kvs = SA;              // [64][264] = 16896  (phase B)
  unsigned short* qs  = SA + 16896;      // [128][40] = 5120   (phase B)
  const int bh = blockIdx.x, b = bh >> 4, h = bh & 15;
  const int l0 = blockIdx.y * 128;
  const int tid = threadIdx.x, lane = tid & 63, w = tid >> 6;
  const int q = lane >> 4, c = lane & 15;
  const int wr = w * 32;

  // --- Phase A: dash + exp, proj staged in two 128-row halves ---
#pragma unroll
  for (int it = 0; it < 4; ++it) {
    int idx = it * 256 + tid;
    int row = idx >> 3, col8 = idx & 7;
    *(uint4*)&Us[row * 72 + col8 * 8] =
        *(const uint4*)&U[((size_t)(b * kL + l0 + row)) * kD + h * kDH + col8 * 8];
  }
#pragma unroll
  for (int it = 0; it < 4; ++it) {       // proj half 0: rows 0..127
    int idx = it * 256 + tid;
    int row = idx >> 3, col8 = idx & 7;
    *(uint4*)&Ps2[row * 72 + col8 * 8] =
        *(const uint4*)&projb[((size_t)(h * kM + row)) * kDH + col8 * 8];
  }
  __syncthreads();

  {
    int row = tid & 127, half = tid >> 7;
    const unsigned short* ur = &Us[row * 72 + half * 32];
    float s = 0.f;
#pragma unroll
    for (int d8 = 0; d8 < 4; ++d8) {
      uint4 raw = *(const uint4*)&ur[d8 * 8];
      const unsigned short* us = (const unsigned short*)&raw;
#pragma unroll
      for (int j = 0; j < 8; ++j) { float v = bf2f(us[j]); s = fmaf(v, v, s); }
    }
    diagp[half * 128 + row] = s;
  }

  f32x4 acc[2][16];
#pragma unroll
  for (int i = 0; i < 2; ++i)
#pragma unroll
    for (int j = 0; j < 16; ++j) acc[i][j] = (f32x4)0.f;

#pragma unroll
  for (int half = 0; half < 2; ++half) {
    if (half == 1) {
      __syncthreads();   // prior Ps2 reads done
#pragma unroll
      for (int it = 0; it < 4; ++it) {   // proj half 1: rows 128..255
        int idx = it * 256 + tid;
        int row = idx >> 3, col8 = idx & 7;
        *(uint4*)&Ps2[row * 72 + col8 * 8] =
            *(const uint4*)&projb[((size_t)(h * kM + 128 + row)) * kDH + col8 * 8];
      }
      __syncthreads();
    }
#pragma unroll
    for (int ks = 0; ks < 2; ++ks) {
      short8 av[2];
#pragma unroll
      for (int i = 0; i < 2; ++i)
        av[i] = *(const short8*)&Us[(wr + i * 16 + c) * 72 + ks * 32 + q * 8];
      short8 bv[8];
#pragma unroll
      for (int jl = 0; jl < 8; ++jl)
        bv[jl] = *(const short8*)&Ps2[(jl * 16 + c) * 72 + ks * 32 + q * 8];
#pragma unroll
      for (int jl = 0; jl < 8; ++jl)
#pragma unroll
        for (int i = 0; i < 2; ++i)
          acc[i][half * 8 + jl] = __builtin_amdgcn_mfma_f32_16x16x32_bf16(
              av[i], bv[jl], acc[i][half * 8 + jl], 0, 0, 0);
    }
  }

  __syncthreads();   // all Us/Ps2 reads complete; alias region reusable
  if (tid < 128) diag[tid] = 0.5f * (diagp[tid] + diagp[128 + tid]);
  // stage kvs: 64 rows x 256 cols = 2048 uint4, 8 per thread
#pragma unroll
  for (int it = 0; it < 8; ++it) {
    int idx = it * 256 + tid;
    int row = idx >> 5, col8 = (idx & 31) * 8;
    *(uint4*)&kvs[row * 264 + col8] =
        *(const uint4*)&KVT[(size_t)bh * (80 * kM) + row * kM + col8];
  }
  // stage ksum row (KVT row 64): 32 uint4
  if (tid < 32)
    *(uint4*)&ksumS[tid * 8] =
        *(const uint4*)&KVT[(size_t)bh * (80 * kM) + 64 * kM + tid * 8];
  __syncthreads();   // diag + kvs + ksum ready (sole Phase B barrier)

  // exp epilogue in registers: acc <- exp(dash - diag - rowmax) * M^-0.5
#pragma unroll
  for (int i = 0; i < 2; ++i)
#pragma unroll
    for (int r = 0; r < 4; ++r) {
      const int lrow = wr + i * 16 + q * 4 + r;
      float mx = -3.4e38f;
#pragma unroll
      for (int j = 0; j < 16; ++j) mx = fmaxf(mx, acc[i][j][r]);
      mx = fmaxf(mx, __shfl_xor(mx, 1, 64));
      mx = fmaxf(mx, __shfl_xor(mx, 2, 64));
      mx = fmaxf(mx, __shfl_xor(mx, 4, 64));
      mx = fmaxf(mx, __shfl_xor(mx, 8, 64));
      const float base = diag[lrow] + mx;
#pragma unroll
      for (int j = 0; j < 16; ++j)
        acc[i][j][r] = __expf(acc[i][j][r] - base) * kInvSqrtM;
    }

  // denominator via VALU + shfl: den[row] = sum_m qf[row][m] * ksum[m]
  float z_[2][4];
#pragma unroll
  for (int i = 0; i < 2; ++i)
#pragma unroll
    for (int r = 0; r < 4; ++r) {
      float d = 0.f;
#pragma unroll
      for (int j = 0; j < 16; ++j)
        d = fmaf(acc[i][j][r], bf2f(ksumS[j * 16 + c]), d);
      d += __shfl_xor(d, 1, 64);
      d += __shfl_xor(d, 2, 64);
      d += __shfl_xor(d, 4, 64);
      d += __shfl_xor(d, 8, 64);
      z_[i][r] = 1.f / (d + kEps);
    }

  // --- Phase B: attn MFMA over 8 m-chunks of 32, BARRIER-FREE (wave-local
  // qs slices; each wave streams through chunks independently) ---
  f32x4 acc2[2][4];
#pragma unroll
  for (int i = 0; i < 2; ++i)
#pragma unroll
    for (int j = 0; j < 4; ++j) acc2[i][j] = (f32x4)0.f;

#pragma unroll
  for (int kk = 0; kk < 8; ++kk) {
#pragma unroll
    for (int i = 0; i < 2; ++i)
#pragma unroll
      for (int jj2 = 0; jj2 < 2; ++jj2) {
        const int jj = kk * 2 + jj2;
#pragma unroll
        for (int r = 0; r < 4; ++r)
          qs[(wr + i * 16 + q * 4 + r) * 40 + jj2 * 16 + c] =
              f2bf(acc[i][jj][r]);
      }
    short8 bv2[4];
#pragma unroll
    for (int j = 0; j < 4; ++j)
      bv2[j] = *(const short8*)&kvs[(j * 16 + c) * 264 + kk * 32 + q * 8];
#pragma unroll
    for (int i = 0; i < 2; ++i) {
      short8 av2 = *(const short8*)&qs[(w * 32 + i * 16 + c) * 40 + q * 8];
#pragma unroll
      for (int j = 0; j < 4; ++j)
        acc2[i][j] = __builtin_amdgcn_mfma_f32_16x16x32_bf16(
            av2, bv2[j], acc2[i][j], 0, 0, 0);
    }
  }

  // epilogue: scale by 1/den, write ATTN
#pragma unroll
  for (int i = 0; i < 2; ++i)
#pragma unroll
    for (int r = 0; r < 4; ++r) {
      const int row = l0 + w * 32 + i * 16 + q * 4 + r;
      const size_t base = ((size_t)(b * kL + row)) * kD + h * kDH;
#pragma unroll
      for (int j = 0; j < 4; ++j)
        ATTN[base + j * 16 + c] = f2bf(acc2[i][j][r] * z_[i][r]);
    }
}

// ---------------------------------------------------------------------------
// kv via MFMA, BK=64 swizzled (r13): per (bh, mtile, split): C[128 m][64 d]
// = KFT tile @ VT tile^T over 512 l, 8 K-steps. ksum from A-fragments.
// ---------------------------------------------------------------------------
__global__ __launch_bounds__(256) void kv_mfma(
    const unsigned short* __restrict__ KFT, const unsigned short* __restrict__ VT,
    float* __restrict__ KVP, float* __restrict__ KSP)
{
  __shared__ unsigned short As[128 * 64];   // 16 KB
  __shared__ unsigned short Bs[64 * 64];    // 8 KB
  const int bh = blockIdx.x, mtile = blockIdx.y, split = blockIdx.z;
  const int tid = threadIdx.x, lane = tid & 63, w = tid >> 6;
  const int q = lane >> 4, c = lane & 15;
  const int l0 = split * 512;
  const unsigned short* Abase = KFT + ((size_t)(bh * kM + mtile * 128)) * kL + l0;
  const unsigned short* Bbase = VT + ((size_t)(bh * kDH)) * kL + l0;
  const int lrow = lane >> 3;
  const int lcol = ((lane & 7) ^ lrow) * 8;   // swizzled global chunk

  f32x4 acc[2][4];
#pragma unroll
  for (int i = 0; i < 2; ++i)
#pragma unroll
    for (int j = 0; j < 4; ++j) acc[i][j] = (f32x4)0.f;
  float ksr[2] = {0.f, 0.f};

  for (int k0 = 0; k0 < 512; k0 += 64) {
#pragma unroll
    for (int i = 0; i < 4; ++i) {
      const int r0 = w * 32 + i * 8;
      gload_lds16(&Abase[(size_t)(r0 + lrow) * kL + k0 + lcol], &As[r0 * 64]);
    }
#pragma unroll
    for (int i = 0; i < 2; ++i) {
      const int r0 = w * 16 + i * 8;
      gload_lds16(&Bbase[(size_t)(r0 + lrow) * kL + k0 + lcol], &Bs[r0 * 64]);
    }
    __syncthreads();
#pragma unroll
    for (int ks = 0; ks < 2; ++ks) {
      short8 av[2], bv[4];
      const int ch = ks * 4 + q;
#pragma unroll
      for (int i = 0; i < 2; ++i) {
        av[i] = *(const short8*)&As[(w * 32 + i * 16 + c) * 64 +
                                    ((ch ^ (c & 7)) * 8)];
#pragma unroll
        for (int e = 0; e < 8; ++e) ksr[i] += bf2f((unsigned short)av[i][e]);
      }
#pragma unroll
      for (int j = 0; j < 4; ++j)
        bv[j] = *(const short8*)&Bs[(j * 16 + c) * 64 + ((ch ^ (c & 7)) * 8)];
#pragma unroll
      for (int i = 0; i < 2; ++i)
#pragma unroll
        for (int j = 0; j < 4; ++j)
          acc[i][j] = __builtin_amdgcn_mfma_f32_16x16x32_bf16(
              av[i], bv[j], acc[i][j], 0, 0, 0);
    }
    __syncthreads();
  }

  const int blk = (bh * 2 + mtile) * 8 + split;
  float* op = KVP + (size_t)blk * (128 * 64);
#pragma unroll
  for (int i = 0; i < 2; ++i)
#pragma unroll
    for (int j = 0; j < 4; ++j)
#pragma unroll
      for (int r = 0; r < 4; ++r)
        op[(w * 32 + i * 16 + q * 4 + r) * 64 + j * 16 + c] = acc[i][j][r];

#pragma unroll
  for (int i = 0; i < 2; ++i) {
    float s = ksr[i];
    s += __shfl_xor(s, 16, 64);
    s += __shfl_xor(s, 32, 64);
    if (q == 0) KSP[blk * 128 + w * 32 + i * 16 + c] = s;
  }
}

// Reduce 8 splits -> KVT' bf16 [bh][80][256]: rows 0..63 = kv^T[d][m],
// row 64 = ksum[m], rows 65..79 = 0 (pad rows kept for layout compat).
__global__ __launch_bounds__(256) void kv_reduce_kernel(
    const float* __restrict__ KVP, const float* __restrict__ KSP,
    unsigned short* __restrict__ KVT)
{
  const int blk = blockIdx.x;            // 32*80
  const int bh = blk / 80, n = blk - bh * 80;
  const int t = threadIdx.x;             // m
  const int mt = t >> 7, ml = t & 127;
  float s = 0.f;
  if (n < 64) {
#pragma unroll
    for (int sp = 0; sp < 8; ++sp)
      s += KVP[((size_t)((bh * 2 + mt) * 8 + sp)) * (128 * 64) + ml * 64 + n];
  } else if (n == 64) {
#pragma unroll
    for (int sp = 0; sp < 8; ++sp)
      s += KSP[((bh * 2 + mt) * 8 + sp) * 128 + ml];
  }
  KVT[(size_t)bh * (80 * kM) + n * kM + t] = f2bf(s);
}

// ---------------------------------------------------------------------------
// GELU (exact) + LayerNorm + 2x nearest-neighbor duplicate write.
// Reads Y as bf16 (written by gemm_wo) — halves the Y round trip.
// ---------------------------------------------------------------------------
__global__ __launch_bounds__(256) void gelu_ln_kernel(
    const unsigned short* __restrict__ Yb, const float* __restrict__ lng,
    const float* __restrict__ lnb, float* __restrict__ OUT)
{
  __shared__ float r1[4], r2[4];
  const int n = blockIdx.x;
  const int tid = threadIdx.x, lane = tid & 63, w = tid >> 6;

  ushort4 yv = ((const ushort4*)(Yb + (size_t)n * kD))[tid];
  float y0 = bf2f(yv.x), y1 = bf2f(yv.y), y2 = bf2f(yv.z), y3 = bf2f(yv.w);
  float g0 = 0.5f * y0 * (1.f + erff(y0 * 0.70710678118654752f));
  float g1 = 0.5f * y1 * (1.f + erff(y1 * 0.70710678118654752f));
  float g2 = 0.5f * y2 * (1.f + erff(y2 * 0.70710678118654752f));
  float g3 = 0.5f * y3 * (1.f + erff(y3 * 0.70710678118654752f));

  float s  = (g0 + g1) + (g2 + g3);
  float ss = (g0 * g0 + g1 * g1) + (g2 * g2 + g3 * g3);
#pragma unroll
  for (int off = 32; off; off >>= 1) {
    s  += __shfl_xor(s, off, 64);
    ss += __shfl_xor(ss, off, 64);
  }
  if (lane == 0) { r1[w] = s; r2[w] = ss; }
  __syncthreads();
  s  = (r1[0] + r1[1]) + (r1[2] + r1[3]);
  ss = (r2[0] + r2[1]) + (r2[2] + r2[3]);
  float mu  = s * (1.f / (float)kD);
  float var = ss * (1.f / (float)kD) - mu * mu;
  float inv = rsqrtf(var + kLnEps);

  float4 gg = ((const float4*)lng)[tid];
  float4 bb = ((const float4*)lnb)[tid];
  float4 o;
  o.x = (g0 - mu) * inv * gg.x + bb.x;
  o.y = (g1 - mu) * inv * gg.y + bb.y;
  o.z = (g2 - mu) * inv * gg.z + bb.z;
  o.w = (g3 - mu) * inv * gg.w + bb.w;

  const int b = n >> 12, l = n & 4095;
  const int cc = tid * 4;
  size_t base = ((size_t)(b * 8192 + 2 * l)) * kD + cc;
  *(float4*)(OUT + base)      = o;
  *(float4*)(OUT + base + kD) = o;
}

// ---------------------------------------------------------------------------
extern "C" void kernel_launch(void* const* d_in, const int* in_sizes, int n_in,
                              void* d_out, int out_size, void* d_ws, size_t ws_size,
                              hipStream_t stream)
{
  (void)in_sizes; (void)n_in; (void)out_size; (void)ws_size;
  const float* x    = (const float*)d_in[0];
  const float* Wq   = (const float*)d_in[1];
  const float* Wk   = (const float*)d_in[2];
  const float* Wv   = (const float*)d_in[3];
  const float* Wo   = (const float*)d_in[4];
  const float* proj = (const float*)d_in[5];
  const float* lng  = (const float*)d_in[6];
  const float* lnb  = (const float*)d_in[7];
  float* out = (float*)d_out;

  // Workspace layout (MB offsets):
  //  0   xb    bf16 [8192,1024]
  //  16  WqkvT bf16 [3072,1024] (Wq/Wk/Wv transposed, stacked)
  //  22  WoT   bf16 [1024,1024] transposed
  //  24  Qb    bf16 [8192,1024] (live until fused_qf_attn)
  //  40  Kb    bf16 (consumed by favor_k; reused as ATTN bf16)
  //  56  VT    bf16 [32 bh][64 d][4096 l]
  //  72  KVP   f32 [512][128*64] 16 MB (dead after kv_reduce; Yb reuses)
  //  136 KFT   bf16 [32 bh][256 m][4096 l]
  //  200 KSP   f32 [512][128]
  //  201 KVT   bf16 [32,80,256]
  //  203 projb bf16 [16,256,64]
  char* ws = (char*)d_ws;
  const size_t MB = 1024 * 1024;
  unsigned short* xb    = (unsigned short*)(ws);
  unsigned short* WqkvT = (unsigned short*)(ws + 16 * MB);
  unsigned short* WoT   = (unsigned short*)(ws + 22 * MB);
  unsigned short* Qb    = (unsigned short*)(ws + 24 * MB);
  unsigned short* Kb    = (unsigned short*)(ws + 40 * MB);
  unsigned short* VT    = (unsigned short*)(ws + 56 * MB);
  float* KVP            = (float*)(ws + 72 * MB);
  unsigned short* KFT   = (unsigned short*)(ws + 136 * MB);
  float* KSP            = (float*)(ws + 200 * MB);
  unsigned short* KVT   = (unsigned short*)(ws + 201 * MB);
  unsigned short* projb = (unsigned short*)(ws + 203 * MB);
  unsigned short* ATTN  = Kb;                       // after favor_k consumed Kb
  unsigned short* Yb    = (unsigned short*)(ws + 72 * MB);  // after KVP dead

  // 1) casts + weight transposes (one launch)
  cast_bf16_kernel<<<(kN * kD) / 1024, 256, 0, stream>>>(x, xb);
  cast_bf16_kernel<<<(kH * kM * kDH) / 1024, 256, 0, stream>>>(proj, projb);
  transpose_cast4_kernel<<<dim3(32, 32, 4), 256, 0, stream>>>(
      Wq, Wk, Wv, Wo, WqkvT, WoT);

  // 2) merged Q+K+V projections (one launch, 1536 blocks = 6/CU)
  gemm_qkv_mfma<<<dim3(24, 64), 256, 0, stream>>>(xb, WqkvT, Qb, Kb, VT);

  // 3) FAVOR-K (stored transposed), then kv / ksum, reduce to KVT'
  favor_k_mfma<<<dim3(32, 32), 256, 0, stream>>>(Kb, projb, KFT);
  kv_mfma<<<dim3(32, 2, 8), 256, 0, stream>>>(KFT, VT, KVP, KSP);
  kv_reduce_kernel<<<32 * 80, 256, 0, stream>>>(KVP, KSP, KVT);

  // 4) fused FAVOR-Q + attention read-out -> bf16 ATTN (QF eliminated)
  fused_qf_attn<<<dim3(32, 32), 256, 0, stream>>>(Qb, projb, KVT, ATTN);

  // 5) output projection (bf16 out, 128x64 tiles, 1024 blocks)
  gemm_wo_mfma<<<dim3(16, 64), 256, 0, stream>>>(ATTN, WoT, Yb);

  // 6) GELU + LayerNorm + 2x duplicate write
  gelu_ln_kernel<<<kN, 256, 0, stream>>>(Yb, lng, lnb, out);
}